// Round 14
// baseline (2245.372 us; speedup 1.0000x reference)
//
#include <hip/hip_runtime.h>
#include <hip/hip_bf16.h>
#include <cstdint>

// Seq2Seq LSTM: B=2048, H=512, I=64, T_enc=256, T_dec=10.
// Persistent kernel, 256 WGs x 512 threads, 16 groups x 16 WGs.
// r13 structure (XCD-local L2 exchange, per-chain wave-level barriers,
// 2x2 wave tile split) + CHAIN PHASE STAGGER: chain B (mh=1) delays ~4.5us
// at start; since chains never inter-sync, the offset persists, so chain A's
// barrier waits overlap chain B's GEMMs on the same SIMDs (and vice versa).

#define B_    2048
#define H_    512
#define I_    64
#define TENC  256
#define TDEC  10
#define WIMG2 65536   // u16 per nt Whh image: 8 blk * 128 row * 64 col

typedef __bf16 bf16x8 __attribute__((ext_vector_type(8)));
typedef float  f32x4  __attribute__((ext_vector_type(4)));
typedef unsigned int u32x4 __attribute__((ext_vector_type(4)));
typedef unsigned int   u32;
typedef unsigned short u16;

union BCV { uint4 u; bf16x8 b; };
union U4B { u32x4 u; bf16x8 b; f32x4 f; };

__device__ __forceinline__ u16 f2bf_rne(float f){
  u32 b = __float_as_uint(f);
  b += 0x7FFFu + ((b >> 16) & 1u);
  return (u16)(b >> 16);
}
__device__ __forceinline__ float bf2f(u16 u){ return __uint_as_float(((u32)u) << 16); }

__device__ __forceinline__ void gl_lds16(const void* g, void* l){
  __builtin_amdgcn_global_load_lds((const __attribute__((address_space(1))) u32*)g,
                                   (__attribute__((address_space(3))) u32*)l, 16, 0, 0);
}

__device__ __forceinline__ float sigm(float x){ return 1.f / (1.f + __expf(-x)); }
__device__ __forceinline__ float tanhfast(float x){ return 1.f - 2.f / (1.f + __expf(2.f * x)); }

#define MFMA16 __builtin_amdgcn_mfma_f32_16x16x32_bf16

#define GLD16(dst, ptr) \
  asm volatile("global_load_dwordx4 %0, %1, off" : "=v"(dst) : "v"(ptr))
#define HST32(ptr, val) \
  asm volatile("global_store_dword %0, %1, off sc0 sc1" :: "v"(ptr), "v"(val) : "memory")
#define GST32(ptr, val) \
  asm volatile("global_store_dword %0, %1, off" :: "v"(ptr), "v"(val) : "memory")

__device__ __forceinline__ bf16x8 ld_bf8(const u16* p){
  BCV cv; cv.u = *(const uint4*)p; return cv.b;
}

__device__ __forceinline__ void cvt8(const float* f, bf16x8& hi, bf16x8& lo){
  u32 hw[4], lw[4];
  #pragma unroll
  for (int e = 0; e < 4; ++e) {
    float f0 = f[e*2], f1 = f[e*2+1];
    u16 h0 = f2bf_rne(f0), h1 = f2bf_rne(f1);
    u16 l0 = f2bf_rne(f0 - bf2f(h0)), l1 = f2bf_rne(f1 - bf2f(h1));
    hw[e] = (u32)h0 | ((u32)h1 << 16);
    lw[e] = (u32)l0 | ((u32)l1 << 16);
  }
  BCV ch, cl;
  ch.u = make_uint4(hw[0], hw[1], hw[2], hw[3]);
  cl.u = make_uint4(lw[0], lw[1], lw[2], lw[3]);
  hi = ch.b; lo = cl.b;
}

// ---------------------------------------------------------------------------
__device__ __forceinline__ int colmap(int c){
  int cl = c & 127, nt = c >> 7;
  return (cl & 3) * 512 + nt * 32 + ((cl >> 5) & 3) * 8 + ((cl >> 2) & 3) * 2 + ((cl >> 4) & 1);
}

__global__ __launch_bounds__(256) void pack_whh(const float* __restrict__ Whh,
                                                u16* __restrict__ img)
{
  int idx = blockIdx.x * 256 + threadIdx.x;
  if (idx >= 16 * WIMG2) return;
  int nt = idx >> 16, rem = idx & 65535;
  int blk = rem >> 13, r2 = rem & 8191;
  int row = r2 >> 6, col = r2 & 63;
  int sc = col >> 3, e = col & 7;
  int lc = ((sc ^ (row & 7)) << 3) + e;
  int n = colmap(nt * 128 + row);
  img[idx] = f2bf_rne(Whh[(size_t)n * 512 + blk * 64 + lc]);
}

__global__ __launch_bounds__(256) void pack_xw(const float* __restrict__ Wih,
                                               u16* __restrict__ xwf)
{
  int idx = blockIdx.x * 256 + threadIdx.x;
  if (idx >= 64 * 8 * 512) return;
  int strip = idx >> 12, rem = idx & 4095;
  int frag = rem >> 9, le = rem & 511;
  int lane = le >> 3, e = le & 7;
  int part = frag >> 2, ks = (frag >> 1) & 1, ni = frag & 1;
  int nt = strip >> 2, nh = strip & 3;
  int c = nt * 128 + nh * 32 + ni * 16 + (lane & 15);
  int k = ks * 32 + (lane >> 4) * 8 + e;
  int n = colmap(c);
  float w = Wih[n * 64 + k];
  u16 h = f2bf_rne(w);
  xwf[idx] = part ? f2bf_rne(w - bf2f(h)) : h;
}

__global__ __launch_bounds__(256) void pack_bias(const float* __restrict__ bih,
                                                 const float* __restrict__ bhh,
                                                 float* __restrict__ bias_pk)
{
  int c = blockIdx.x * 256 + threadIdx.x;
  if (c >= 2048) return;
  int n = colmap(c);
  bias_pk[c] = bih[n] + bhh[n];
}

__global__ __launch_bounds__(256) void transpose_wd(const float* __restrict__ Wd,
                                                    float* __restrict__ WdT)
{
  int idx = blockIdx.x * 256 + threadIdx.x;
  if (idx >= I_ * H_) return;
  int n = idx >> 9, k = idx & 511;
  WdT[k * 64 + n] = Wd[idx];
}

__global__ __launch_bounds__(64) void prefrag_x(const float* __restrict__ x,
                                                u16* __restrict__ xf)
{
  int wg = blockIdx.x;
  int t = wg >> 7, rb = wg & 127;
  int l = threadIdx.x;
  __shared__ float tile[16][65];
  #pragma unroll
  for (int row = 0; row < 16; ++row)
    tile[row][l] = x[(((size_t)(rb * 16 + row)) * 256 + t) * 64 + l];
  __syncthreads();
  int lr = l & 15, lgp = l >> 4;
  size_t base = ((size_t)t * 128 + rb) * 2048;
  #pragma unroll
  for (int kf = 0; kf < 2; ++kf) {
    float fv[8];
    #pragma unroll
    for (int e2 = 0; e2 < 8; ++e2) fv[e2] = tile[lr][kf * 32 + lgp * 8 + e2];
    bf16x8 hi, lo;
    cvt8(fv, hi, lo);
    BCV ch, cl; ch.b = hi; cl.b = lo;
    *(uint4*)(xf + base + (0 * 2 + kf) * 512 + l * 8) = ch.u;
    *(uint4*)(xf + base + (1 * 2 + kf) * 512 + l * 8) = cl.u;
  }
}

// ---------------------------------------------------------------------------
__device__ __forceinline__ void stage_whh(const u16* src, char* smem, int tid){
  #pragma unroll
  for (int it = 0; it < 16; ++it)
    gl_lds16(src + it * 4096 + tid * 8, smem + it * 8192 + tid * 16);
}

__device__ __forceinline__ void load_xw2(const u16* xwbase, int cs, int lane,
                                         bf16x8 (&whiR)[2][4], bf16x8 (&wloR)[2][4]){
  #pragma unroll
  for (int part = 0; part < 2; ++part)
    #pragma unroll
    for (int ks = 0; ks < 2; ++ks)
      #pragma unroll
      for (int ni = 0; ni < 4; ++ni) {
        int strip = cs * 2 + (ni >> 1);
        bf16x8 v = ld_bf8(xwbase + (size_t)strip * 4096 +
                          ((part * 2 + ks) * 2 + (ni & 1)) * 512 + lane * 8);
        if (part == 0) whiR[ks][ni] = v; else wloR[ks][ni] = v;
      }
}

__device__ __forceinline__ void wave_arrive(u32* gcnt, u32* lcnt, int lane,
                                            int fast, int& ev){
  asm volatile("s_waitcnt vmcnt(0)" ::: "memory");
  u32 old = 0;
  if (lane == 0) old = atomicAdd(lcnt, 1u);
  old = __builtin_amdgcn_readfirstlane(old);
  if ((old & 3u) == 3u) {
    if (lane == 0) {
      if (fast) {
        asm volatile("global_atomic_add %0, %1, off" :: "v"(gcnt), "v"(1u) : "memory");
      } else {
        __hip_atomic_fetch_add(gcnt, 1u, __ATOMIC_RELAXED, __HIP_MEMORY_SCOPE_AGENT);
      }
    }
    asm volatile("s_waitcnt vmcnt(0)" ::: "memory");
  }
  ++ev;
}

__device__ __forceinline__ void wave_wait(u32* gcnt, u32* lflag, int lane,
                                          int leader, int fast, int ev){
  u32 target = (u32)ev * 16u;
  if (leader) {
    if (fast) {
      for (;;) {
        u32 v = 0;
        if (lane == 0)
          asm volatile("global_atomic_or %0, %1, %2, off sc0\n\ts_waitcnt vmcnt(0)"
                       : "=v"(v) : "v"(gcnt), "v"(0u) : "memory");
        v = __builtin_amdgcn_readfirstlane(v);
        if (v >= target) break;
        __builtin_amdgcn_s_sleep(1);
      }
      asm volatile("buffer_inv" ::: "memory");
    } else {
      for (;;) {
        u32 v = 0;
        if (lane == 0)
          v = __hip_atomic_load(gcnt, __ATOMIC_RELAXED, __HIP_MEMORY_SCOPE_AGENT);
        v = __builtin_amdgcn_readfirstlane(v);
        if (v >= target) break;
        __builtin_amdgcn_s_sleep(1);
      }
      __builtin_amdgcn_fence(__ATOMIC_ACQUIRE, "agent");
    }
    if (lane == 0)
      __hip_atomic_store(lflag, (u32)ev, __ATOMIC_RELAXED, __HIP_MEMORY_SCOPE_WORKGROUP);
    asm volatile("s_waitcnt lgkmcnt(0)" ::: "memory");
  } else {
    for (;;) {
      u32 f = 0;
      if (lane == 0)
        f = __hip_atomic_load(lflag, __ATOMIC_RELAXED, __HIP_MEMORY_SCOPE_WORKGROUP);
      f = __builtin_amdgcn_readfirstlane(f);
      if (f >= (u32)ev) break;
      __builtin_amdgcn_s_sleep(1);
    }
  }
}

__device__ __forceinline__ void issue_h2(const u16* h_in, int rbase, int lane,
                                         int kb, U4B (&dst)[4]){
  #pragma unroll
  for (int ks = 0; ks < 2; ++ks)
    #pragma unroll
    for (int mi = 0; mi < 2; ++mi) {
      const u16* p = h_in + (size_t)(rbase + mi) * 8192 + (kb * 2 + ks) * 512
                     + (lane >> 4) * 128 + (lane & 15) * 8;
      GLD16(dst[ks * 2 + mi].u, p);
    }
}

// ---------------------------------------------------------------------------
__global__ __launch_bounds__(512, 1) void lstm_persistent(
    const float* __restrict__ x, const u16* __restrict__ xf, int use_xf,
    const u16* __restrict__ WhhE, const u16* __restrict__ WhhD,
    const u16* __restrict__ xwE, const u16* __restrict__ xwD,
    const float* __restrict__ biasE, const float* __restrict__ biasD,
    u16* __restrict__ hb0, u16* __restrict__ hb1,
    float* __restrict__ dout,
    const float* __restrict__ WdT, const float* __restrict__ ldb,
    const float* __restrict__ loW, const float* __restrict__ lob,
    float* __restrict__ out, u32* __restrict__ cnt, u32* __restrict__ xcc)
{
  extern __shared__ char smem[];
  __shared__ u32 chaincnt[2];
  __shared__ u32 chainflag[2];
  const int tid = threadIdx.x;
  const int bid = blockIdx.x;
  const int mt = ((bid & 7) << 1) | ((bid >> 3) & 1);
  const int nt = bid >> 4;
  const int wid = tid >> 6, lane = tid & 63;
  const int mh = wid >> 2, sub = wid & 3;    // chain = mh; sub -> 2x2 tile
  const int rs = sub >> 1, cs = sub & 1;
  const int leader = (sub == 0) ? 1 : 0;
  const int lr = lane & 15, lgp = lane >> 4;
  const int rbase = mt * 8 + mh * 4 + rs * 2;
  u32* ccnt = cnt + (mt * 2 + mh) * 16;
  u32* pcnt = cnt + 512 + mt * 16;
  u32* cflag = &chainflag[mh];

  stage_whh(WhhE + (size_t)nt * WIMG2, smem, tid);
  bf16x8 whiR[2][4], wloR[2][4];
  load_xw2(xwE + (size_t)nt * 16384, cs, lane, whiR, wloR);
  f32x4 bvec[4];
  #pragma unroll
  for (int ni = 0; ni < 4; ++ni)
    bvec[ni] = *(const f32x4*)(biasE + nt * 128 + cs * 64 + ni * 16 + lgp * 4);

  // ---- prologue: publish XCC id, safe barrier, verify group co-location ----
  u32 myxcc;
  asm volatile("s_getreg_b32 %0, hwreg(HW_REG_XCC_ID)" : "=s"(myxcc));
  if (tid == 0) {
    chaincnt[0] = 0; chaincnt[1] = 0;
    chainflag[0] = 0; chainflag[1] = 0;
    HST32(xcc + bid, myxcc);
  }
  asm volatile("s_waitcnt vmcnt(0)" ::: "memory");
  __syncthreads();
  if (tid == 0) {
    __hip_atomic_fetch_add(pcnt, 1u, __ATOMIC_RELAXED, __HIP_MEMORY_SCOPE_AGENT);
    while (__hip_atomic_load(pcnt, __ATOMIC_RELAXED, __HIP_MEMORY_SCOPE_AGENT) < 16u)
      __builtin_amdgcn_s_sleep(1);
    __builtin_amdgcn_fence(__ATOMIC_ACQUIRE, "agent");
  }
  __syncthreads();
  int fast = 1;
  {
    int gb = (mt >> 1) | ((mt & 1) << 3);
    #pragma unroll
    for (int k = 0; k < 16; ++k) {
      u32 v;
      asm volatile("global_load_dword %0, %1, off sc0 sc1\n\ts_waitcnt vmcnt(0)"
                   : "=v"(v) : "v"(xcc + gb + k * 16));
      fast &= (v == myxcc) ? 1 : 0;
    }
  }
  __syncthreads();

  // ---- CHAIN PHASE STAGGER: chain B starts ~half a step late; chains never
  // inter-sync, so the offset persists and A's waits overlap B's GEMMs ----
  if (mh == 1) {
    #pragma unroll 1
    for (int i = 0; i < 10; ++i) __builtin_amdgcn_s_sleep(15);
  }

  float creg[2][4];
  #pragma unroll
  for (int a = 0; a < 2; ++a)
    #pragma unroll
    for (int b = 0; b < 4; ++b) creg[a][b] = 0.f;

  int ev = 0;

  // ================= encoder: x -> wait -> h -> epi -> arrive =================
  for (int t = 0; t < TENC; ++t) {
    const u16* __restrict__ h_in  = (t & 1) ? hb1 : hb0;
    u16*       __restrict__ h_out = (t & 1) ? hb0 : hb1;

    f32x4 acc[2][4];
    #pragma unroll
    for (int a = 0; a < 2; ++a)
      #pragma unroll
      for (int b = 0; b < 4; ++b) acc[a][b] = (f32x4){0.f, 0.f, 0.f, 0.f};

    if (use_xf) {
      #pragma unroll
      for (int mi = 0; mi < 2; ++mi) {
        const u16* fb = xf + ((size_t)t * 128 + rbase + mi) * 2048;
        bf16x8 x0 = ld_bf8(fb +        lane * 8);
        bf16x8 x1 = ld_bf8(fb +  512 + lane * 8);
        bf16x8 l0 = ld_bf8(fb + 1024 + lane * 8);
        bf16x8 l1 = ld_bf8(fb + 1536 + lane * 8);
        #pragma unroll
        for (int ni = 0; ni < 4; ++ni) {
          acc[mi][ni] = MFMA16(whiR[0][ni], x0, acc[mi][ni], 0, 0, 0);
          acc[mi][ni] = MFMA16(wloR[0][ni], x0, acc[mi][ni], 0, 0, 0);
          acc[mi][ni] = MFMA16(whiR[1][ni], x1, acc[mi][ni], 0, 0, 0);
          acc[mi][ni] = MFMA16(wloR[1][ni], x1, acc[mi][ni], 0, 0, 0);
          acc[mi][ni] = MFMA16(whiR[0][ni], l0, acc[mi][ni], 0, 0, 0);
          acc[mi][ni] = MFMA16(whiR[1][ni], l1, acc[mi][ni], 0, 0, 0);
        }
      }
    } else {
      #pragma unroll
      for (int mi = 0; mi < 2; ++mi) {
        int brow = (rbase + mi) * 16 + lr;
        const float* p = x + ((size_t)brow * 256 + t) * 64;
        float fv[8];
        #pragma unroll
        for (int ks = 0; ks < 2; ++ks) {
          #pragma unroll
          for (int e = 0; e < 8; ++e) fv[e] = p[ks * 32 + lgp * 8 + e];
          bf16x8 xh, xl;
          cvt8(fv, xh, xl);
          #pragma unroll
          for (int ni = 0; ni < 4; ++ni) {
            acc[mi][ni] = MFMA16(whiR[ks][ni], xh, acc[mi][ni], 0, 0, 0);
            acc[mi][ni] = MFMA16(wloR[ks][ni], xh, acc[mi][ni], 0, 0, 0);
            acc[mi][ni] = MFMA16(whiR[ks][ni], xl, acc[mi][ni], 0, 0, 0);
          }
        }
      }
    }

    wave_wait(ccnt, cflag, lane, leader, fast, ev);

    {
      U4B hr[3][4];
      issue_h2(h_in, rbase, lane, 0, hr[0]);
      issue_h2(h_in, rbase, lane, 1, hr[1]);
      #pragma unroll
      for (int kb = 0; kb < 8; ++kb) {
        if (kb < 6) issue_h2(h_in, rbase, lane, kb + 2, hr[(kb + 2) % 3]);
        if (kb < 6)       { asm volatile("s_waitcnt vmcnt(8)" ::: "memory"); }
        else if (kb == 6) { asm volatile("s_waitcnt vmcnt(4)" ::: "memory"); }
        else              { asm volatile("s_waitcnt vmcnt(0)" ::: "memory"); }
        __builtin_amdgcn_sched_barrier(0);
        #pragma unroll
        for (int ks = 0; ks < 2; ++ks) {
          bf16x8 wf[4];
          #pragma unroll
          for (int ni = 0; ni < 4; ++ni) {
            int crow = cs * 64 + ni * 16 + lr;
            wf[ni] = *(const bf16x8*)(smem + kb * 16384 + crow * 128 +
                                      (((ks * 4 + lgp) ^ (crow & 7)) << 4));
          }
          #pragma unroll
          for (int mi = 0; mi < 2; ++mi)
            #pragma unroll
            for (int ni = 0; ni < 4; ++ni)
              acc[mi][ni] = MFMA16(wf[ni], hr[kb % 3][ks * 2 + mi].b, acc[mi][ni], 0, 0, 0);
        }
      }
    }

    #pragma unroll
    for (int mi = 0; mi < 2; ++mi) {
      #pragma unroll
      for (int nip = 0; nip < 2; ++nip) {
        float hn2[2];
        #pragma unroll
        for (int s2 = 0; s2 < 2; ++s2) {
          int ni = nip * 2 + s2;
          f32x4 g = acc[mi][ni];
          float gi = g[0] + bvec[ni][0];
          float gf = g[1] + bvec[ni][1];
          float gg = g[2] + bvec[ni][2];
          float go = g[3] + bvec[ni][3];
          float c0 = creg[mi][ni];
          float cn = sigm(gf) * c0 + sigm(gi) * tanhfast(gg);
          hn2[s2] = sigm(go) * tanhfast(cn);
          creg[mi][ni] = cn;
        }
        u32 pk = (u32)f2bf_rne(hn2[0]) | ((u32)f2bf_rne(hn2[1]) << 16);
        u16* p = h_out + (size_t)(rbase + mi) * 8192 + nt * 512 +
                 (cs * 2 + nip) * 128 + lr * 8 + lgp * 2;
        if (fast) { GST32(p, pk); } else { HST32(p, pk); }
      }
    }
    wave_arrive(ccnt, &chaincnt[mh], lane, fast, ev);
  }

  // ================= weight swap =================
  __syncthreads();
  stage_whh(WhhD + (size_t)nt * WIMG2, smem, tid);
  load_xw2(xwD + (size_t)nt * 16384, cs, lane, whiR, wloR);
  #pragma unroll
  for (int ni = 0; ni < 4; ++ni)
    bvec[ni] = *(const f32x4*)(biasD + nt * 128 + cs * 64 + ni * 16 + lgp * 4);
  asm volatile("s_waitcnt vmcnt(0)" ::: "memory");
  __syncthreads();

  // ================= decoder =================
  for (int d = 0; d < TDEC; ++d) {
    int t = TENC + d;
    const u16* __restrict__ h_in  = (t & 1) ? hb1 : hb0;
    u16*       __restrict__ h_out = (t & 1) ? hb0 : hb1;

    f32x4 acc[2][4];
    #pragma unroll
    for (int a = 0; a < 2; ++a)
      #pragma unroll
      for (int b = 0; b < 4; ++b) acc[a][b] = (f32x4){0.f, 0.f, 0.f, 0.f};

    if (d == 0) {
      if (use_xf) {
        #pragma unroll
        for (int mi = 0; mi < 2; ++mi) {
          const u16* fb = xf + ((size_t)255 * 128 + rbase + mi) * 2048;
          bf16x8 x0 = ld_bf8(fb +        lane * 8);
          bf16x8 x1 = ld_bf8(fb +  512 + lane * 8);
          bf16x8 l0 = ld_bf8(fb + 1024 + lane * 8);
          bf16x8 l1 = ld_bf8(fb + 1536 + lane * 8);
          #pragma unroll
          for (int ni = 0; ni < 4; ++ni) {
            acc[mi][ni] = MFMA16(whiR[0][ni], x0, acc[mi][ni], 0, 0, 0);
            acc[mi][ni] = MFMA16(wloR[0][ni], x0, acc[mi][ni], 0, 0, 0);
            acc[mi][ni] = MFMA16(whiR[1][ni], x1, acc[mi][ni], 0, 0, 0);
            acc[mi][ni] = MFMA16(wloR[1][ni], x1, acc[mi][ni], 0, 0, 0);
            acc[mi][ni] = MFMA16(whiR[0][ni], l0, acc[mi][ni], 0, 0, 0);
            acc[mi][ni] = MFMA16(whiR[1][ni], l1, acc[mi][ni], 0, 0, 0);
          }
        }
      } else {
        #pragma unroll
        for (int mi = 0; mi < 2; ++mi) {
          int brow = (rbase + mi) * 16 + lr;
          const float* p = x + ((size_t)brow * 256 + 255) * 64;
          float fv[8];
          #pragma unroll
          for (int ks = 0; ks < 2; ++ks) {
            #pragma unroll
            for (int e = 0; e < 8; ++e) fv[e] = p[ks * 32 + lgp * 8 + e];
            bf16x8 xh, xl;
            cvt8(fv, xh, xl);
            #pragma unroll
            for (int ni = 0; ni < 4; ++ni) {
              acc[mi][ni] = MFMA16(whiR[ks][ni], xh, acc[mi][ni], 0, 0, 0);
              acc[mi][ni] = MFMA16(wloR[ks][ni], xh, acc[mi][ni], 0, 0, 0);
              acc[mi][ni] = MFMA16(whiR[ks][ni], xl, acc[mi][ni], 0, 0, 0);
            }
          }
        }
      }
      wave_wait(ccnt, cflag, lane, leader, fast, ev);
    } else {
      wave_wait(ccnt, cflag, lane, leader, fast, ev);
      #pragma unroll
      for (int mi = 0; mi < 2; ++mi) {
        int brow = (rbase + mi) * 16 + lr;
        const float* p = dout + (size_t)brow * 64 + lgp * 8;
        #pragma unroll
        for (int ks = 0; ks < 2; ++ks) {
          float fv[8];
          float4 a0 = *(const float4*)(p + ks * 32);
          float4 a1 = *(const float4*)(p + ks * 32 + 4);
          fv[0]=a0.x; fv[1]=a0.y; fv[2]=a0.z; fv[3]=a0.w;
          fv[4]=a1.x; fv[5]=a1.y; fv[6]=a1.z; fv[7]=a1.w;
          bf16x8 xh, xl;
          cvt8(fv, xh, xl);
          #pragma unroll
          for (int ni = 0; ni < 4; ++ni) {
            acc[mi][ni] = MFMA16(whiR[ks][ni], xh, acc[mi][ni], 0, 0, 0);
            acc[mi][ni] = MFMA16(wloR[ks][ni], xh, acc[mi][ni], 0, 0, 0);
            acc[mi][ni] = MFMA16(whiR[ks][ni], xl, acc[mi][ni], 0, 0, 0);
          }
        }
      }
    }

    {
      U4B hr[3][4];
      issue_h2(h_in, rbase, lane, 0, hr[0]);
      issue_h2(h_in, rbase, lane, 1, hr[1]);
      #pragma unroll
      for (int kb = 0; kb < 8; ++kb) {
        if (kb < 6) issue_h2(h_in, rbase, lane, kb + 2, hr[(kb + 2) % 3]);
        if (kb < 6)       { asm volatile("s_waitcnt vmcnt(8)" ::: "memory"); }
        else if (kb == 6) { asm volatile("s_waitcnt vmcnt(4)" ::: "memory"); }
        else              { asm volatile("s_waitcnt vmcnt(0)" ::: "memory"); }
        __builtin_amdgcn_sched_barrier(0);
        #pragma unroll
        for (int ks = 0; ks < 2; ++ks) {
          bf16x8 wf[4];
          #pragma unroll
          for (int ni = 0; ni < 4; ++ni) {
            int crow = cs * 64 + ni * 16 + lr;
            wf[ni] = *(const bf16x8*)(smem + kb * 16384 + crow * 128 +
                                      (((ks * 4 + lgp) ^ (crow & 7)) << 4));
          }
          #pragma unroll
          for (int mi = 0; mi < 2; ++mi)
            #pragma unroll
            for (int ni = 0; ni < 4; ++ni)
              acc[mi][ni] = MFMA16(wf[ni], hr[kb % 3][ks * 2 + mi].b, acc[mi][ni], 0, 0, 0);
        }
      }
    }

    #pragma unroll
    for (int mi = 0; mi < 2; ++mi) {
      #pragma unroll
      for (int nip = 0; nip < 2; ++nip) {
        float hn2[2];
        #pragma unroll
        for (int s2 = 0; s2 < 2; ++s2) {
          int ni = nip * 2 + s2;
          f32x4 g = acc[mi][ni];
          float gi = g[0] + bvec[ni][0];
          float gf = g[1] + bvec[ni][1];
          float gg = g[2] + bvec[ni][2];
          float go = g[3] + bvec[ni][3];
          float c0 = creg[mi][ni];
          float cn = sigm(gf) * c0 + sigm(gi) * tanhfast(gg);
          hn2[s2] = sigm(go) * tanhfast(cn);
          creg[mi][ni] = cn;
        }
        u32 pk = (u32)f2bf_rne(hn2[0]) | ((u32)f2bf_rne(hn2[1]) << 16);
        u16* p = h_out + (size_t)(rbase + mi) * 8192 + nt * 512 +
                 (cs * 2 + nip) * 128 + lr * 8 + lgp * 2;
        if (fast) { GST32(p, pk); } else { HST32(p, pk); }
      }
    }
    wave_arrive(ccnt, &chaincnt[mh], lane, fast, ev);
    wave_wait(ccnt, cflag, lane, leader, fast, ev);

    {
      int b = mt * 128 + mh * 64 + nt * 4 + sub;
      int rb = b >> 4, lrb = b & 15;
      const u16* hbase = h_out + (size_t)rb * 8192 + lrb * 8;
      float a2 = ldb[lane];
      #pragma unroll 8
      for (int q = 0; q < 64; ++q) {
        uint4 hv = *(const uint4*)(hbase + q * 128);
        #pragma unroll
        for (int e = 0; e < 8; ++e) {
          float h8 = bf2f(((const u16*)&hv)[e]);
          a2 += h8 * WdT[(q * 8 + e) * 64 + lane];
        }
      }
      float* dp = dout + (size_t)b * 64 + lane;
      if (fast) { GST32(dp, __float_as_uint(a2)); } else { HST32(dp, __float_as_uint(a2)); }
      float yv = a2 * loW[lane];
      #pragma unroll
      for (int o2 = 32; o2; o2 >>= 1) yv += __shfl_xor(yv, o2, 64);
      if (lane == 0) out[(size_t)b * TDEC + d] = yv + lob[0];
    }
    if (d < TDEC - 1) wave_arrive(ccnt, &chaincnt[mh], lane, fast, ev);
  }
}

// ---------------------------------------------------------------------------
extern "C" void kernel_launch(void* const* d_in, const int* in_sizes, int n_in,
                              void* d_out, int out_size, void* d_ws, size_t ws_size,
                              hipStream_t stream)
{
  const float* x    = (const float*)d_in[0];
  const float* eWih = (const float*)d_in[1];
  const float* eWhh = (const float*)d_in[2];
  const float* ebih = (const float*)d_in[3];
  const float* ebhh = (const float*)d_in[4];
  const float* dWih = (const float*)d_in[5];
  const float* dWhh = (const float*)d_in[6];
  const float* dbih = (const float*)d_in[7];
  const float* dbhh = (const float*)d_in[8];
  const float* ldW  = (const float*)d_in[9];
  const float* ldbp = (const float*)d_in[10];
  const float* loW  = (const float*)d_in[11];
  const float* lob  = (const float*)d_in[12];
  float* out = (float*)d_out;

  char* ws = (char*)d_ws;
  size_t o = 0;
  auto alloc = [&](size_t bytes){ size_t r = o; o += (bytes + 255) & ~(size_t)255; return r; };
  u16*   WhhIE = (u16*)  (ws + alloc((size_t)16 * WIMG2 * 2));
  u16*   WhhID = (u16*)  (ws + alloc((size_t)16 * WIMG2 * 2));
  u16*   xwE   = (u16*)  (ws + alloc((size_t)64 * 8 * 512 * 2));
  u16*   xwD   = (u16*)  (ws + alloc((size_t)64 * 8 * 512 * 2));
  float* biasE = (float*)(ws + alloc(2048 * 4));
  float* biasD = (float*)(ws + alloc(2048 * 4));
  float* WdT   = (float*)(ws + alloc((size_t)I_ * H_ * 4));
  u16*   hb0   = (u16*)  (ws + alloc((size_t)B_ * H_ * 2));
  u16*   hb1   = (u16*)  (ws + alloc((size_t)B_ * H_ * 2));
  float* dout  = (float*)(ws + alloc((size_t)B_ * I_ * 4));
  u32*   cnt   = (u32*)  (ws + alloc(4096));
  u32*   xcc   = (u32*)  (ws + alloc(1024));
  size_t xf_off = alloc((size_t)256 * 128 * 2048 * 2);   // 128 MiB
  int use_xf = (o <= ws_size) ? 1 : 0;
  u16* xf = use_xf ? (u16*)(ws + xf_off) : (u16*)(ws);
  (void)in_sizes; (void)n_in; (void)out_size;

  pack_whh<<<(16 * WIMG2 + 255) / 256, 256, 0, stream>>>(eWhh, WhhIE);
  pack_whh<<<(16 * WIMG2 + 255) / 256, 256, 0, stream>>>(dWhh, WhhID);
  pack_xw<<<(64 * 8 * 512 + 255) / 256, 256, 0, stream>>>(eWih, xwE);
  pack_xw<<<(64 * 8 * 512 + 255) / 256, 256, 0, stream>>>(dWih, xwD);
  pack_bias<<<8, 256, 0, stream>>>(ebih, ebhh, biasE);
  pack_bias<<<8, 256, 0, stream>>>(dbih, dbhh, biasD);
  transpose_wd<<<(I_ * H_ + 255) / 256, 256, 0, stream>>>(ldW, WdT);
  if (use_xf)
    prefrag_x<<<256 * 128, 64, 0, stream>>>(x, xf);
  (void)hipMemsetAsync(hb0, 0, (size_t)B_ * H_ * 2, stream);
  (void)hipMemsetAsync(cnt, 0, 4096, stream);

  static bool attr_set = false;
  if (!attr_set) {
    (void)hipFuncSetAttribute((const void*)lstm_persistent,
                              hipFuncAttributeMaxDynamicSharedMemorySize, 131072);
    attr_set = true;
  }

  const float* xp = x; const u16* xfp = xf; int uxf = use_xf;
  const u16 *we = WhhIE, *wd = WhhID, *xe = xwE, *xd = xwD;
  const float *be = biasE, *bd = biasD, *wdt = WdT, *lb = ldbp, *lw = loW, *lo2 = lob;
  u16 *h0 = hb0, *h1 = hb1;
  float *dp = dout, *op = out;
  u32* cp = cnt; u32* xc = xcc;
  void* kargs[] = { (void*)&xp, (void*)&xfp, (void*)&uxf, (void*)&we, (void*)&wd,
                    (void*)&xe, (void*)&xd, (void*)&be, (void*)&bd,
                    (void*)&h0, (void*)&h1, (void*)&dp, (void*)&wdt,
                    (void*)&lb, (void*)&lw, (void*)&lo2, (void*)&op, (void*)&cp,
                    (void*)&xc };
  hipError_t e = hipLaunchCooperativeKernel((const void*)lstm_persistent,
                                            dim3(256), dim3(512), kargs, 131072, stream);
  if (e != hipSuccess) {
    lstm_persistent<<<256, 512, 131072, stream>>>(xp, xfp, uxf, we, wd, xe, xd,
                                                  be, bd, h0, h1, dp, wdt,
                                                  lb, lw, lo2, op, cp, xc);
  }
}

// Round 15
// 1996.415 us; speedup vs baseline: 1.1247x; 1.1247x over previous
//
#include <hip/hip_runtime.h>
#include <hip/hip_bf16.h>
#include <cstdint>

// Seq2Seq LSTM: B=2048, H=512, I=64, T_enc=256, T_dec=10.
// Persistent kernel, 256 WGs x 512 threads, 16 groups x 16 WGs.
// r13 structure (XCD-local L2 exchange verified via HW_REG_XCC_ID, per-chain
// wave-level barriers, 2x2 wave tile split) + VALU-diet epilogue:
//  - sigm/tanh use v_rcp_f32 (rcpf builtin) instead of IEEE divide
//  - bias pre-loaded into the MFMA accumulator (no per-gate adds)
//  - h pack via v_cvt_pk_bf16_f32 (1 instr, RNE)

#define B_    2048
#define H_    512
#define I_    64
#define TENC  256
#define TDEC  10
#define WIMG2 65536   // u16 per nt Whh image: 8 blk * 128 row * 64 col

typedef __bf16 bf16x8 __attribute__((ext_vector_type(8)));
typedef float  f32x4  __attribute__((ext_vector_type(4)));
typedef unsigned int u32x4 __attribute__((ext_vector_type(4)));
typedef unsigned int   u32;
typedef unsigned short u16;

union BCV { uint4 u; bf16x8 b; };
union U4B { u32x4 u; bf16x8 b; f32x4 f; };

__device__ __forceinline__ u16 f2bf_rne(float f){
  u32 b = __float_as_uint(f);
  b += 0x7FFFu + ((b >> 16) & 1u);
  return (u16)(b >> 16);
}
__device__ __forceinline__ float bf2f(u16 u){ return __uint_as_float(((u32)u) << 16); }

__device__ __forceinline__ void gl_lds16(const void* g, void* l){
  __builtin_amdgcn_global_load_lds((const __attribute__((address_space(1))) u32*)g,
                                   (__attribute__((address_space(3))) u32*)l, 16, 0, 0);
}

// fast transcendentals: v_exp (via __expf) + v_rcp (1 instr, ~1ulp)
__device__ __forceinline__ float sigm(float x){
  return __builtin_amdgcn_rcpf(1.f + __expf(-x));
}
__device__ __forceinline__ float tanhfast(float x){
  return 1.f - 2.f * __builtin_amdgcn_rcpf(1.f + __expf(2.f * x));
}
// packed f32x2 -> bf16x2 (RNE), single VALU op
__device__ __forceinline__ u32 pk_bf16(float lo, float hi){
  u32 r;
  asm("v_cvt_pk_bf16_f32 %0, %1, %2" : "=v"(r) : "v"(lo), "v"(hi));
  return r;
}

#define MFMA16 __builtin_amdgcn_mfma_f32_16x16x32_bf16

#define GLD16(dst, ptr) \
  asm volatile("global_load_dwordx4 %0, %1, off" : "=v"(dst) : "v"(ptr))
#define HST32(ptr, val) \
  asm volatile("global_store_dword %0, %1, off sc0 sc1" :: "v"(ptr), "v"(val) : "memory")
#define GST32(ptr, val) \
  asm volatile("global_store_dword %0, %1, off" :: "v"(ptr), "v"(val) : "memory")

__device__ __forceinline__ bf16x8 ld_bf8(const u16* p){
  BCV cv; cv.u = *(const uint4*)p; return cv.b;
}

__device__ __forceinline__ void cvt8(const float* f, bf16x8& hi, bf16x8& lo){
  u32 hw[4], lw[4];
  #pragma unroll
  for (int e = 0; e < 4; ++e) {
    float f0 = f[e*2], f1 = f[e*2+1];
    u16 h0 = f2bf_rne(f0), h1 = f2bf_rne(f1);
    u16 l0 = f2bf_rne(f0 - bf2f(h0)), l1 = f2bf_rne(f1 - bf2f(h1));
    hw[e] = (u32)h0 | ((u32)h1 << 16);
    lw[e] = (u32)l0 | ((u32)l1 << 16);
  }
  BCV ch, cl;
  ch.u = make_uint4(hw[0], hw[1], hw[2], hw[3]);
  cl.u = make_uint4(lw[0], lw[1], lw[2], lw[3]);
  hi = ch.b; lo = cl.b;
}

// ---------------------------------------------------------------------------
__device__ __forceinline__ int colmap(int c){
  int cl = c & 127, nt = c >> 7;
  return (cl & 3) * 512 + nt * 32 + ((cl >> 5) & 3) * 8 + ((cl >> 2) & 3) * 2 + ((cl >> 4) & 1);
}

__global__ __launch_bounds__(256) void pack_whh(const float* __restrict__ Whh,
                                                u16* __restrict__ img)
{
  int idx = blockIdx.x * 256 + threadIdx.x;
  if (idx >= 16 * WIMG2) return;
  int nt = idx >> 16, rem = idx & 65535;
  int blk = rem >> 13, r2 = rem & 8191;
  int row = r2 >> 6, col = r2 & 63;
  int sc = col >> 3, e = col & 7;
  int lc = ((sc ^ (row & 7)) << 3) + e;
  int n = colmap(nt * 128 + row);
  img[idx] = f2bf_rne(Whh[(size_t)n * 512 + blk * 64 + lc]);
}

__global__ __launch_bounds__(256) void pack_xw(const float* __restrict__ Wih,
                                               u16* __restrict__ xwf)
{
  int idx = blockIdx.x * 256 + threadIdx.x;
  if (idx >= 64 * 8 * 512) return;
  int strip = idx >> 12, rem = idx & 4095;
  int frag = rem >> 9, le = rem & 511;
  int lane = le >> 3, e = le & 7;
  int part = frag >> 2, ks = (frag >> 1) & 1, ni = frag & 1;
  int nt = strip >> 2, nh = strip & 3;
  int c = nt * 128 + nh * 32 + ni * 16 + (lane & 15);
  int k = ks * 32 + (lane >> 4) * 8 + e;
  int n = colmap(c);
  float w = Wih[n * 64 + k];
  u16 h = f2bf_rne(w);
  xwf[idx] = part ? f2bf_rne(w - bf2f(h)) : h;
}

__global__ __launch_bounds__(256) void pack_bias(const float* __restrict__ bih,
                                                 const float* __restrict__ bhh,
                                                 float* __restrict__ bias_pk)
{
  int c = blockIdx.x * 256 + threadIdx.x;
  if (c >= 2048) return;
  int n = colmap(c);
  bias_pk[c] = bih[n] + bhh[n];
}

__global__ __launch_bounds__(256) void transpose_wd(const float* __restrict__ Wd,
                                                    float* __restrict__ WdT)
{
  int idx = blockIdx.x * 256 + threadIdx.x;
  if (idx >= I_ * H_) return;
  int n = idx >> 9, k = idx & 511;
  WdT[k * 64 + n] = Wd[idx];
}

__global__ __launch_bounds__(64) void prefrag_x(const float* __restrict__ x,
                                                u16* __restrict__ xf)
{
  int wg = blockIdx.x;
  int t = wg >> 7, rb = wg & 127;
  int l = threadIdx.x;
  __shared__ float tile[16][65];
  #pragma unroll
  for (int row = 0; row < 16; ++row)
    tile[row][l] = x[(((size_t)(rb * 16 + row)) * 256 + t) * 64 + l];
  __syncthreads();
  int lr = l & 15, lgp = l >> 4;
  size_t base = ((size_t)t * 128 + rb) * 2048;
  #pragma unroll
  for (int kf = 0; kf < 2; ++kf) {
    float fv[8];
    #pragma unroll
    for (int e2 = 0; e2 < 8; ++e2) fv[e2] = tile[lr][kf * 32 + lgp * 8 + e2];
    bf16x8 hi, lo;
    cvt8(fv, hi, lo);
    BCV ch, cl; ch.b = hi; cl.b = lo;
    *(uint4*)(xf + base + (0 * 2 + kf) * 512 + l * 8) = ch.u;
    *(uint4*)(xf + base + (1 * 2 + kf) * 512 + l * 8) = cl.u;
  }
}

// ---------------------------------------------------------------------------
__device__ __forceinline__ void stage_whh(const u16* src, char* smem, int tid){
  #pragma unroll
  for (int it = 0; it < 16; ++it)
    gl_lds16(src + it * 4096 + tid * 8, smem + it * 8192 + tid * 16);
}

__device__ __forceinline__ void load_xw2(const u16* xwbase, int cs, int lane,
                                         bf16x8 (&whiR)[2][4], bf16x8 (&wloR)[2][4]){
  #pragma unroll
  for (int part = 0; part < 2; ++part)
    #pragma unroll
    for (int ks = 0; ks < 2; ++ks)
      #pragma unroll
      for (int ni = 0; ni < 4; ++ni) {
        int strip = cs * 2 + (ni >> 1);
        bf16x8 v = ld_bf8(xwbase + (size_t)strip * 4096 +
                          ((part * 2 + ks) * 2 + (ni & 1)) * 512 + lane * 8);
        if (part == 0) whiR[ks][ni] = v; else wloR[ks][ni] = v;
      }
}

__device__ __forceinline__ void wave_arrive(u32* gcnt, u32* lcnt, int lane,
                                            int fast, int& ev){
  asm volatile("s_waitcnt vmcnt(0)" ::: "memory");
  u32 old = 0;
  if (lane == 0) old = atomicAdd(lcnt, 1u);
  old = __builtin_amdgcn_readfirstlane(old);
  if ((old & 3u) == 3u) {
    if (lane == 0) {
      if (fast) {
        asm volatile("global_atomic_add %0, %1, off" :: "v"(gcnt), "v"(1u) : "memory");
      } else {
        __hip_atomic_fetch_add(gcnt, 1u, __ATOMIC_RELAXED, __HIP_MEMORY_SCOPE_AGENT);
      }
    }
    asm volatile("s_waitcnt vmcnt(0)" ::: "memory");
  }
  ++ev;
}

__device__ __forceinline__ void wave_wait(u32* gcnt, u32* lflag, int lane,
                                          int leader, int fast, int ev){
  u32 target = (u32)ev * 16u;
  if (leader) {
    if (fast) {
      for (;;) {
        u32 v = 0;
        if (lane == 0)
          asm volatile("global_atomic_or %0, %1, %2, off sc0\n\ts_waitcnt vmcnt(0)"
                       : "=v"(v) : "v"(gcnt), "v"(0u) : "memory");
        v = __builtin_amdgcn_readfirstlane(v);
        if (v >= target) break;
        __builtin_amdgcn_s_sleep(1);
      }
      asm volatile("buffer_inv" ::: "memory");
    } else {
      for (;;) {
        u32 v = 0;
        if (lane == 0)
          v = __hip_atomic_load(gcnt, __ATOMIC_RELAXED, __HIP_MEMORY_SCOPE_AGENT);
        v = __builtin_amdgcn_readfirstlane(v);
        if (v >= target) break;
        __builtin_amdgcn_s_sleep(1);
      }
      __builtin_amdgcn_fence(__ATOMIC_ACQUIRE, "agent");
    }
    if (lane == 0)
      __hip_atomic_store(lflag, (u32)ev, __ATOMIC_RELAXED, __HIP_MEMORY_SCOPE_WORKGROUP);
    asm volatile("s_waitcnt lgkmcnt(0)" ::: "memory");
  } else {
    for (;;) {
      u32 f = 0;
      if (lane == 0)
        f = __hip_atomic_load(lflag, __ATOMIC_RELAXED, __HIP_MEMORY_SCOPE_WORKGROUP);
      f = __builtin_amdgcn_readfirstlane(f);
      if (f >= (u32)ev) break;
      __builtin_amdgcn_s_sleep(1);
    }
  }
}

__device__ __forceinline__ void issue_h2(const u16* h_in, int rbase, int lane,
                                         int kb, U4B (&dst)[4]){
  #pragma unroll
  for (int ks = 0; ks < 2; ++ks)
    #pragma unroll
    for (int mi = 0; mi < 2; ++mi) {
      const u16* p = h_in + (size_t)(rbase + mi) * 8192 + (kb * 2 + ks) * 512
                     + (lane >> 4) * 128 + (lane & 15) * 8;
      GLD16(dst[ks * 2 + mi].u, p);
    }
}

// ---------------------------------------------------------------------------
__global__ __launch_bounds__(512, 1) void lstm_persistent(
    const float* __restrict__ x, const u16* __restrict__ xf, int use_xf,
    const u16* __restrict__ WhhE, const u16* __restrict__ WhhD,
    const u16* __restrict__ xwE, const u16* __restrict__ xwD,
    const float* __restrict__ biasE, const float* __restrict__ biasD,
    u16* __restrict__ hb0, u16* __restrict__ hb1,
    float* __restrict__ dout,
    const float* __restrict__ WdT, const float* __restrict__ ldb,
    const float* __restrict__ loW, const float* __restrict__ lob,
    float* __restrict__ out, u32* __restrict__ cnt, u32* __restrict__ xcc)
{
  extern __shared__ char smem[];
  __shared__ u32 chaincnt[2];
  __shared__ u32 chainflag[2];
  const int tid = threadIdx.x;
  const int bid = blockIdx.x;
  const int mt = ((bid & 7) << 1) | ((bid >> 3) & 1);
  const int nt = bid >> 4;
  const int wid = tid >> 6, lane = tid & 63;
  const int mh = wid >> 2, sub = wid & 3;    // chain = mh; sub -> 2x2 tile
  const int rs = sub >> 1, cs = sub & 1;
  const int leader = (sub == 0) ? 1 : 0;
  const int lr = lane & 15, lgp = lane >> 4;
  const int rbase = mt * 8 + mh * 4 + rs * 2;
  u32* ccnt = cnt + (mt * 2 + mh) * 16;
  u32* pcnt = cnt + 512 + mt * 16;
  u32* cflag = &chainflag[mh];

  stage_whh(WhhE + (size_t)nt * WIMG2, smem, tid);
  bf16x8 whiR[2][4], wloR[2][4];
  load_xw2(xwE + (size_t)nt * 16384, cs, lane, whiR, wloR);
  f32x4 bvec[4];
  #pragma unroll
  for (int ni = 0; ni < 4; ++ni)
    bvec[ni] = *(const f32x4*)(biasE + nt * 128 + cs * 64 + ni * 16 + lgp * 4);

  // ---- prologue: publish XCC id, safe barrier, verify group co-location ----
  u32 myxcc;
  asm volatile("s_getreg_b32 %0, hwreg(HW_REG_XCC_ID)" : "=s"(myxcc));
  if (tid == 0) {
    chaincnt[0] = 0; chaincnt[1] = 0;
    chainflag[0] = 0; chainflag[1] = 0;
    HST32(xcc + bid, myxcc);
  }
  asm volatile("s_waitcnt vmcnt(0)" ::: "memory");
  __syncthreads();
  if (tid == 0) {
    __hip_atomic_fetch_add(pcnt, 1u, __ATOMIC_RELAXED, __HIP_MEMORY_SCOPE_AGENT);
    while (__hip_atomic_load(pcnt, __ATOMIC_RELAXED, __HIP_MEMORY_SCOPE_AGENT) < 16u)
      __builtin_amdgcn_s_sleep(1);
    __builtin_amdgcn_fence(__ATOMIC_ACQUIRE, "agent");
  }
  __syncthreads();
  int fast = 1;
  {
    int gb = (mt >> 1) | ((mt & 1) << 3);
    #pragma unroll
    for (int k = 0; k < 16; ++k) {
      u32 v;
      asm volatile("global_load_dword %0, %1, off sc0 sc1\n\ts_waitcnt vmcnt(0)"
                   : "=v"(v) : "v"(xcc + gb + k * 16));
      fast &= (v == myxcc) ? 1 : 0;
    }
  }
  __syncthreads();

  float creg[2][4];
  #pragma unroll
  for (int a = 0; a < 2; ++a)
    #pragma unroll
    for (int b = 0; b < 4; ++b) creg[a][b] = 0.f;

  int ev = 0;

  // ================= encoder: x -> wait -> h -> epi -> arrive =================
  for (int t = 0; t < TENC; ++t) {
    const u16* __restrict__ h_in  = (t & 1) ? hb1 : hb0;
    u16*       __restrict__ h_out = (t & 1) ? hb0 : hb1;

    f32x4 acc[2][4];
    #pragma unroll
    for (int a = 0; a < 2; ++a)
      #pragma unroll
      for (int b = 0; b < 4; ++b) acc[a][b] = bvec[b];   // bias pre-loaded

    if (use_xf) {
      #pragma unroll
      for (int mi = 0; mi < 2; ++mi) {
        const u16* fb = xf + ((size_t)t * 128 + rbase + mi) * 2048;
        bf16x8 x0 = ld_bf8(fb +        lane * 8);
        bf16x8 x1 = ld_bf8(fb +  512 + lane * 8);
        bf16x8 l0 = ld_bf8(fb + 1024 + lane * 8);
        bf16x8 l1 = ld_bf8(fb + 1536 + lane * 8);
        #pragma unroll
        for (int ni = 0; ni < 4; ++ni) {
          acc[mi][ni] = MFMA16(whiR[0][ni], x0, acc[mi][ni], 0, 0, 0);
          acc[mi][ni] = MFMA16(wloR[0][ni], x0, acc[mi][ni], 0, 0, 0);
          acc[mi][ni] = MFMA16(whiR[1][ni], x1, acc[mi][ni], 0, 0, 0);
          acc[mi][ni] = MFMA16(wloR[1][ni], x1, acc[mi][ni], 0, 0, 0);
          acc[mi][ni] = MFMA16(whiR[0][ni], l0, acc[mi][ni], 0, 0, 0);
          acc[mi][ni] = MFMA16(whiR[1][ni], l1, acc[mi][ni], 0, 0, 0);
        }
      }
    } else {
      #pragma unroll
      for (int mi = 0; mi < 2; ++mi) {
        int brow = (rbase + mi) * 16 + lr;
        const float* p = x + ((size_t)brow * 256 + t) * 64;
        float fv[8];
        #pragma unroll
        for (int ks = 0; ks < 2; ++ks) {
          #pragma unroll
          for (int e = 0; e < 8; ++e) fv[e] = p[ks * 32 + lgp * 8 + e];
          bf16x8 xh, xl;
          cvt8(fv, xh, xl);
          #pragma unroll
          for (int ni = 0; ni < 4; ++ni) {
            acc[mi][ni] = MFMA16(whiR[ks][ni], xh, acc[mi][ni], 0, 0, 0);
            acc[mi][ni] = MFMA16(wloR[ks][ni], xh, acc[mi][ni], 0, 0, 0);
            acc[mi][ni] = MFMA16(whiR[ks][ni], xl, acc[mi][ni], 0, 0, 0);
          }
        }
      }
    }

    wave_wait(ccnt, cflag, lane, leader, fast, ev);

    {
      U4B hr[3][4];
      issue_h2(h_in, rbase, lane, 0, hr[0]);
      issue_h2(h_in, rbase, lane, 1, hr[1]);
      #pragma unroll
      for (int kb = 0; kb < 8; ++kb) {
        if (kb < 6) issue_h2(h_in, rbase, lane, kb + 2, hr[(kb + 2) % 3]);
        if (kb < 6)       { asm volatile("s_waitcnt vmcnt(8)" ::: "memory"); }
        else if (kb == 6) { asm volatile("s_waitcnt vmcnt(4)" ::: "memory"); }
        else              { asm volatile("s_waitcnt vmcnt(0)" ::: "memory"); }
        __builtin_amdgcn_sched_barrier(0);
        #pragma unroll
        for (int ks = 0; ks < 2; ++ks) {
          bf16x8 wf[4];
          #pragma unroll
          for (int ni = 0; ni < 4; ++ni) {
            int crow = cs * 64 + ni * 16 + lr;
            wf[ni] = *(const bf16x8*)(smem + kb * 16384 + crow * 128 +
                                      (((ks * 4 + lgp) ^ (crow & 7)) << 4));
          }
          #pragma unroll
          for (int mi = 0; mi < 2; ++mi)
            #pragma unroll
            for (int ni = 0; ni < 4; ++ni)
              acc[mi][ni] = MFMA16(wf[ni], hr[kb % 3][ks * 2 + mi].b, acc[mi][ni], 0, 0, 0);
        }
      }
    }

    #pragma unroll
    for (int mi = 0; mi < 2; ++mi) {
      #pragma unroll
      for (int nip = 0; nip < 2; ++nip) {
        float hn2[2];
        #pragma unroll
        for (int s2 = 0; s2 < 2; ++s2) {
          int ni = nip * 2 + s2;
          f32x4 g = acc[mi][ni];
          float c0 = creg[mi][ni];
          float cn = sigm(g[1]) * c0 + sigm(g[0]) * tanhfast(g[2]);
          hn2[s2] = sigm(g[3]) * tanhfast(cn);
          creg[mi][ni] = cn;
        }
        u32 pk = pk_bf16(hn2[0], hn2[1]);
        u16* p = h_out + (size_t)(rbase + mi) * 8192 + nt * 512 +
                 (cs * 2 + nip) * 128 + lr * 8 + lgp * 2;
        if (fast) { GST32(p, pk); } else { HST32(p, pk); }
      }
    }
    wave_arrive(ccnt, &chaincnt[mh], lane, fast, ev);
  }

  // ================= weight swap =================
  __syncthreads();
  stage_whh(WhhD + (size_t)nt * WIMG2, smem, tid);
  load_xw2(xwD + (size_t)nt * 16384, cs, lane, whiR, wloR);
  #pragma unroll
  for (int ni = 0; ni < 4; ++ni)
    bvec[ni] = *(const f32x4*)(biasD + nt * 128 + cs * 64 + ni * 16 + lgp * 4);
  asm volatile("s_waitcnt vmcnt(0)" ::: "memory");
  __syncthreads();

  // ================= decoder =================
  for (int d = 0; d < TDEC; ++d) {
    int t = TENC + d;
    const u16* __restrict__ h_in  = (t & 1) ? hb1 : hb0;
    u16*       __restrict__ h_out = (t & 1) ? hb0 : hb1;

    f32x4 acc[2][4];
    #pragma unroll
    for (int a = 0; a < 2; ++a)
      #pragma unroll
      for (int b = 0; b < 4; ++b) acc[a][b] = bvec[b];

    if (d == 0) {
      if (use_xf) {
        #pragma unroll
        for (int mi = 0; mi < 2; ++mi) {
          const u16* fb = xf + ((size_t)255 * 128 + rbase + mi) * 2048;
          bf16x8 x0 = ld_bf8(fb +        lane * 8);
          bf16x8 x1 = ld_bf8(fb +  512 + lane * 8);
          bf16x8 l0 = ld_bf8(fb + 1024 + lane * 8);
          bf16x8 l1 = ld_bf8(fb + 1536 + lane * 8);
          #pragma unroll
          for (int ni = 0; ni < 4; ++ni) {
            acc[mi][ni] = MFMA16(whiR[0][ni], x0, acc[mi][ni], 0, 0, 0);
            acc[mi][ni] = MFMA16(wloR[0][ni], x0, acc[mi][ni], 0, 0, 0);
            acc[mi][ni] = MFMA16(whiR[1][ni], x1, acc[mi][ni], 0, 0, 0);
            acc[mi][ni] = MFMA16(wloR[1][ni], x1, acc[mi][ni], 0, 0, 0);
            acc[mi][ni] = MFMA16(whiR[0][ni], l0, acc[mi][ni], 0, 0, 0);
            acc[mi][ni] = MFMA16(whiR[1][ni], l1, acc[mi][ni], 0, 0, 0);
          }
        }
      } else {
        #pragma unroll
        for (int mi = 0; mi < 2; ++mi) {
          int brow = (rbase + mi) * 16 + lr;
          const float* p = x + ((size_t)brow * 256 + 255) * 64;
          float fv[8];
          #pragma unroll
          for (int ks = 0; ks < 2; ++ks) {
            #pragma unroll
            for (int e = 0; e < 8; ++e) fv[e] = p[ks * 32 + lgp * 8 + e];
            bf16x8 xh, xl;
            cvt8(fv, xh, xl);
            #pragma unroll
            for (int ni = 0; ni < 4; ++ni) {
              acc[mi][ni] = MFMA16(whiR[ks][ni], xh, acc[mi][ni], 0, 0, 0);
              acc[mi][ni] = MFMA16(wloR[ks][ni], xh, acc[mi][ni], 0, 0, 0);
              acc[mi][ni] = MFMA16(whiR[ks][ni], xl, acc[mi][ni], 0, 0, 0);
            }
          }
        }
      }
      wave_wait(ccnt, cflag, lane, leader, fast, ev);
    } else {
      wave_wait(ccnt, cflag, lane, leader, fast, ev);
      #pragma unroll
      for (int mi = 0; mi < 2; ++mi) {
        int brow = (rbase + mi) * 16 + lr;
        const float* p = dout + (size_t)brow * 64 + lgp * 8;
        #pragma unroll
        for (int ks = 0; ks < 2; ++ks) {
          float fv[8];
          float4 a0 = *(const float4*)(p + ks * 32);
          float4 a1 = *(const float4*)(p + ks * 32 + 4);
          fv[0]=a0.x; fv[1]=a0.y; fv[2]=a0.z; fv[3]=a0.w;
          fv[4]=a1.x; fv[5]=a1.y; fv[6]=a1.z; fv[7]=a1.w;
          bf16x8 xh, xl;
          cvt8(fv, xh, xl);
          #pragma unroll
          for (int ni = 0; ni < 4; ++ni) {
            acc[mi][ni] = MFMA16(whiR[ks][ni], xh, acc[mi][ni], 0, 0, 0);
            acc[mi][ni] = MFMA16(wloR[ks][ni], xh, acc[mi][ni], 0, 0, 0);
            acc[mi][ni] = MFMA16(whiR[ks][ni], xl, acc[mi][ni], 0, 0, 0);
          }
        }
      }
    }

    {
      U4B hr[3][4];
      issue_h2(h_in, rbase, lane, 0, hr[0]);
      issue_h2(h_in, rbase, lane, 1, hr[1]);
      #pragma unroll
      for (int kb = 0; kb < 8; ++kb) {
        if (kb < 6) issue_h2(h_in, rbase, lane, kb + 2, hr[(kb + 2) % 3]);
        if (kb < 6)       { asm volatile("s_waitcnt vmcnt(8)" ::: "memory"); }
        else if (kb == 6) { asm volatile("s_waitcnt vmcnt(4)" ::: "memory"); }
        else              { asm volatile("s_waitcnt vmcnt(0)" ::: "memory"); }
        __builtin_amdgcn_sched_barrier(0);
        #pragma unroll
        for (int ks = 0; ks < 2; ++ks) {
          bf16x8 wf[4];
          #pragma unroll
          for (int ni = 0; ni < 4; ++ni) {
            int crow = cs * 64 + ni * 16 + lr;
            wf[ni] = *(const bf16x8*)(smem + kb * 16384 + crow * 128 +
                                      (((ks * 4 + lgp) ^ (crow & 7)) << 4));
          }
          #pragma unroll
          for (int mi = 0; mi < 2; ++mi)
            #pragma unroll
            for (int ni = 0; ni < 4; ++ni)
              acc[mi][ni] = MFMA16(wf[ni], hr[kb % 3][ks * 2 + mi].b, acc[mi][ni], 0, 0, 0);
        }
      }
    }

    #pragma unroll
    for (int mi = 0; mi < 2; ++mi) {
      #pragma unroll
      for (int nip = 0; nip < 2; ++nip) {
        float hn2[2];
        #pragma unroll
        for (int s2 = 0; s2 < 2; ++s2) {
          int ni = nip * 2 + s2;
          f32x4 g = acc[mi][ni];
          float c0 = creg[mi][ni];
          float cn = sigm(g[1]) * c0 + sigm(g[0]) * tanhfast(g[2]);
          hn2[s2] = sigm(g[3]) * tanhfast(cn);
          creg[mi][ni] = cn;
        }
        u32 pk = pk_bf16(hn2[0], hn2[1]);
        u16* p = h_out + (size_t)(rbase + mi) * 8192 + nt * 512 +
                 (cs * 2 + nip) * 128 + lr * 8 + lgp * 2;
        if (fast) { GST32(p, pk); } else { HST32(p, pk); }
      }
    }
    wave_arrive(ccnt, &chaincnt[mh], lane, fast, ev);
    wave_wait(ccnt, cflag, lane, leader, fast, ev);

    {
      int b = mt * 128 + mh * 64 + nt * 4 + sub;
      int rb = b >> 4, lrb = b & 15;
      const u16* hbase = h_out + (size_t)rb * 8192 + lrb * 8;
      float a2 = ldb[lane];
      #pragma unroll 8
      for (int q = 0; q < 64; ++q) {
        uint4 hv = *(const uint4*)(hbase + q * 128);
        #pragma unroll
        for (int e = 0; e < 8; ++e) {
          float h8 = bf2f(((const u16*)&hv)[e]);
          a2 += h8 * WdT[(q * 8 + e) * 64 + lane];
        }
      }
      float* dp = dout + (size_t)b * 64 + lane;
      if (fast) { GST32(dp, __float_as_uint(a2)); } else { HST32(dp, __float_as_uint(a2)); }
      float yv = a2 * loW[lane];
      #pragma unroll
      for (int o2 = 32; o2; o2 >>= 1) yv += __shfl_xor(yv, o2, 64);
      if (lane == 0) out[(size_t)b * TDEC + d] = yv + lob[0];
    }
    if (d < TDEC - 1) wave_arrive(ccnt, &chaincnt[mh], lane, fast, ev);
  }
}

// ---------------------------------------------------------------------------
extern "C" void kernel_launch(void* const* d_in, const int* in_sizes, int n_in,
                              void* d_out, int out_size, void* d_ws, size_t ws_size,
                              hipStream_t stream)
{
  const float* x    = (const float*)d_in[0];
  const float* eWih = (const float*)d_in[1];
  const float* eWhh = (const float*)d_in[2];
  const float* ebih = (const float*)d_in[3];
  const float* ebhh = (const float*)d_in[4];
  const float* dWih = (const float*)d_in[5];
  const float* dWhh = (const float*)d_in[6];
  const float* dbih = (const float*)d_in[7];
  const float* dbhh = (const float*)d_in[8];
  const float* ldW  = (const float*)d_in[9];
  const float* ldbp = (const float*)d_in[10];
  const float* loW  = (const float*)d_in[11];
  const float* lob  = (const float*)d_in[12];
  float* out = (float*)d_out;

  char* ws = (char*)d_ws;
  size_t o = 0;
  auto alloc = [&](size_t bytes){ size_t r = o; o += (bytes + 255) & ~(size_t)255; return r; };
  u16*   WhhIE = (u16*)  (ws + alloc((size_t)16 * WIMG2 * 2));
  u16*   WhhID = (u16*)  (ws + alloc((size_t)16 * WIMG2 * 2));
  u16*   xwE   = (u16*)  (ws + alloc((size_t)64 * 8 * 512 * 2));
  u16*   xwD   = (u16*)  (ws + alloc((size_t)64 * 8 * 512 * 2));
  float* biasE = (float*)(ws + alloc(2048 * 4));
  float* biasD = (float*)(ws + alloc(2048 * 4));
  float* WdT   = (float*)(ws + alloc((size_t)I_ * H_ * 4));
  u16*   hb0   = (u16*)  (ws + alloc((size_t)B_ * H_ * 2));
  u16*   hb1   = (u16*)  (ws + alloc((size_t)B_ * H_ * 2));
  float* dout  = (float*)(ws + alloc((size_t)B_ * I_ * 4));
  u32*   cnt   = (u32*)  (ws + alloc(4096));
  u32*   xcc   = (u32*)  (ws + alloc(1024));
  size_t xf_off = alloc((size_t)256 * 128 * 2048 * 2);   // 128 MiB
  int use_xf = (o <= ws_size) ? 1 : 0;
  u16* xf = use_xf ? (u16*)(ws + xf_off) : (u16*)(ws);
  (void)in_sizes; (void)n_in; (void)out_size;

  pack_whh<<<(16 * WIMG2 + 255) / 256, 256, 0, stream>>>(eWhh, WhhIE);
  pack_whh<<<(16 * WIMG2 + 255) / 256, 256, 0, stream>>>(dWhh, WhhID);
  pack_xw<<<(64 * 8 * 512 + 255) / 256, 256, 0, stream>>>(eWih, xwE);
  pack_xw<<<(64 * 8 * 512 + 255) / 256, 256, 0, stream>>>(dWih, xwD);
  pack_bias<<<8, 256, 0, stream>>>(ebih, ebhh, biasE);
  pack_bias<<<8, 256, 0, stream>>>(dbih, dbhh, biasD);
  transpose_wd<<<(I_ * H_ + 255) / 256, 256, 0, stream>>>(ldW, WdT);
  if (use_xf)
    prefrag_x<<<256 * 128, 64, 0, stream>>>(x, xf);
  (void)hipMemsetAsync(hb0, 0, (size_t)B_ * H_ * 2, stream);
  (void)hipMemsetAsync(cnt, 0, 4096, stream);

  static bool attr_set = false;
  if (!attr_set) {
    (void)hipFuncSetAttribute((const void*)lstm_persistent,
                              hipFuncAttributeMaxDynamicSharedMemorySize, 131072);
    attr_set = true;
  }

  const float* xp = x; const u16* xfp = xf; int uxf = use_xf;
  const u16 *we = WhhIE, *wd = WhhID, *xe = xwE, *xd = xwD;
  const float *be = biasE, *bd = biasD, *wdt = WdT, *lb = ldbp, *lw = loW, *lo2 = lob;
  u16 *h0 = hb0, *h1 = hb1;
  float *dp = dout, *op = out;
  u32* cp = cnt; u32* xc = xcc;
  void* kargs[] = { (void*)&xp, (void*)&xfp, (void*)&uxf, (void*)&we, (void*)&wd,
                    (void*)&xe, (void*)&xd, (void*)&be, (void*)&bd,
                    (void*)&h0, (void*)&h1, (void*)&dp, (void*)&wdt,
                    (void*)&lb, (void*)&lw, (void*)&lo2, (void*)&op, (void*)&cp,
                    (void*)&xc };
  hipError_t e = hipLaunchCooperativeKernel((const void*)lstm_persistent,
                                            dim3(256), dim3(512), kargs, 131072, stream);
  if (e != hipSuccess) {
    lstm_persistent<<<256, 512, 131072, stream>>>(xp, xfp, uxf, we, wd, xe, xd,
                                                  be, bd, h0, h1, dp, wdt,
                                                  lb, lw, lo2, op, cp, xc);
  }
}

// Round 16
// 1448.902 us; speedup vs baseline: 1.5497x; 1.3779x over previous
//
#include <hip/hip_runtime.h>
#include <hip/hip_bf16.h>
#include <cstdint>

// Seq2Seq LSTM: B=2048, H=512, I=64, T_enc=256, T_dec=10.
// Persistent kernel, 256 WGs x 512 threads, 16 groups x 16 WGs.
// r15 structure (XCD-local L2 exchange verified via HW_REG_XCC_ID, per-chain
// wave-level barriers, 2x2 wave tile split, VALU-diet epilogue) plus:
//  - x-part in fp16 (mfma_f32_16x16x32_f16): 1 MFMA instead of 3 (bf16 hi/lo)
//  - xf register prefetch issued before the epilogue (hidden under epi+arrive)
//  - h-load pipeline depth 4 (vmcnt(12) schedule)

#define B_    2048
#define H_    512
#define I_    64
#define TENC  256
#define TDEC  10
#define WIMG2 65536   // u16 per nt Whh image: 8 blk * 128 row * 64 col

typedef __bf16 bf16x8 __attribute__((ext_vector_type(8)));
typedef _Float16 f16x8 __attribute__((ext_vector_type(8)));
typedef float  f32x4  __attribute__((ext_vector_type(4)));
typedef unsigned int u32x4 __attribute__((ext_vector_type(4)));
typedef unsigned int   u32;
typedef unsigned short u16;

union BCV { uint4 u; bf16x8 b; };
union U4B { u32x4 u; bf16x8 b; f32x4 f; };
union U4H { u32x4 u; f16x8 h; };
union HB  { _Float16 h; u16 u; };

__device__ __forceinline__ u16 f2bf_rne(float f){
  u32 b = __float_as_uint(f);
  b += 0x7FFFu + ((b >> 16) & 1u);
  return (u16)(b >> 16);
}
__device__ __forceinline__ float bf2f(u16 u){ return __uint_as_float(((u32)u) << 16); }

__device__ __forceinline__ void gl_lds16(const void* g, void* l){
  __builtin_amdgcn_global_load_lds((const __attribute__((address_space(1))) u32*)g,
                                   (__attribute__((address_space(3))) u32*)l, 16, 0, 0);
}

// fast transcendentals: v_exp + v_rcp (~1ulp each)
__device__ __forceinline__ float sigm(float x){
  return __builtin_amdgcn_rcpf(1.f + __expf(-x));
}
__device__ __forceinline__ float tanhfast(float x){
  return 1.f - 2.f * __builtin_amdgcn_rcpf(1.f + __expf(2.f * x));
}
__device__ __forceinline__ u32 pk_bf16(float lo, float hi){
  u32 r;
  asm("v_cvt_pk_bf16_f32 %0, %1, %2" : "=v"(r) : "v"(lo), "v"(hi));
  return r;
}

#define MFMA16  __builtin_amdgcn_mfma_f32_16x16x32_bf16
#define MFMA16H __builtin_amdgcn_mfma_f32_16x16x32_f16

#define GLD16(dst, ptr) \
  asm volatile("global_load_dwordx4 %0, %1, off" : "=v"(dst) : "v"(ptr))
#define HST32(ptr, val) \
  asm volatile("global_store_dword %0, %1, off sc0 sc1" :: "v"(ptr), "v"(val) : "memory")
#define GST32(ptr, val) \
  asm volatile("global_store_dword %0, %1, off" :: "v"(ptr), "v"(val) : "memory")

__device__ __forceinline__ f16x8 ld_f8(const u16* p){
  U4H cv; cv.u = *(const u32x4*)p; return cv.h;
}
__device__ __forceinline__ f16x8 cvtf16(const float* fv){
  f16x8 r;
  #pragma unroll
  for (int e = 0; e < 8; ++e) r[e] = (_Float16)fv[e];
  return r;
}

// ---------------------------------------------------------------------------
__device__ __forceinline__ int colmap(int c){
  int cl = c & 127, nt = c >> 7;
  return (cl & 3) * 512 + nt * 32 + ((cl >> 5) & 3) * 8 + ((cl >> 2) & 3) * 2 + ((cl >> 4) & 1);
}

__global__ __launch_bounds__(256) void pack_whh(const float* __restrict__ Whh,
                                                u16* __restrict__ img)
{
  int idx = blockIdx.x * 256 + threadIdx.x;
  if (idx >= 16 * WIMG2) return;
  int nt = idx >> 16, rem = idx & 65535;
  int blk = rem >> 13, r2 = rem & 8191;
  int row = r2 >> 6, col = r2 & 63;
  int sc = col >> 3, e = col & 7;
  int lc = ((sc ^ (row & 7)) << 3) + e;
  int n = colmap(nt * 128 + row);
  img[idx] = f2bf_rne(Whh[(size_t)n * 512 + blk * 64 + lc]);
}

// x-weights in fp16 fragment layout: per nt, 4 strips(nh) x 4 frags(ks*2+ni) x 512
__global__ __launch_bounds__(256) void pack_xw(const float* __restrict__ Wih,
                                               u16* __restrict__ xwf)
{
  int idx = blockIdx.x * 256 + threadIdx.x;
  if (idx >= 64 * 4 * 512) return;
  int strip = idx >> 11, rem = idx & 2047;
  int frag = rem >> 9, le = rem & 511;
  int lane = le >> 3, e = le & 7;
  int ks = frag >> 1, ni = frag & 1;
  int nt = strip >> 2, nh = strip & 3;
  int c = nt * 128 + nh * 32 + ni * 16 + (lane & 15);
  int k = ks * 32 + (lane >> 4) * 8 + e;
  int n = colmap(c);
  HB hb; hb.h = (_Float16)Wih[n * 64 + k];
  xwf[idx] = hb.u;
}

__global__ __launch_bounds__(256) void pack_bias(const float* __restrict__ bih,
                                                 const float* __restrict__ bhh,
                                                 float* __restrict__ bias_pk)
{
  int c = blockIdx.x * 256 + threadIdx.x;
  if (c >= 2048) return;
  int n = colmap(c);
  bias_pk[c] = bih[n] + bhh[n];
}

__global__ __launch_bounds__(256) void transpose_wd(const float* __restrict__ Wd,
                                                    float* __restrict__ WdT)
{
  int idx = blockIdx.x * 256 + threadIdx.x;
  if (idx >= I_ * H_) return;
  int n = idx >> 9, k = idx & 511;
  WdT[k * 64 + n] = Wd[idx];
}

// x -> fp16 fragment layout: xf[(t*128+rb)*1024 + kf*512 + lane*8]
__global__ __launch_bounds__(64) void prefrag_x(const float* __restrict__ x,
                                                u16* __restrict__ xf)
{
  int wg = blockIdx.x;
  int t = wg >> 7, rb = wg & 127;
  int l = threadIdx.x;
  __shared__ float tile[16][65];
  #pragma unroll
  for (int row = 0; row < 16; ++row)
    tile[row][l] = x[(((size_t)(rb * 16 + row)) * 256 + t) * 64 + l];
  __syncthreads();
  int lr = l & 15, lgp = l >> 4;
  size_t base = ((size_t)t * 128 + rb) * 1024;
  #pragma unroll
  for (int kf = 0; kf < 2; ++kf) {
    float fv[8];
    #pragma unroll
    for (int e2 = 0; e2 < 8; ++e2) fv[e2] = tile[lr][kf * 32 + lgp * 8 + e2];
    U4H cv; cv.h = cvtf16(fv);
    *(u32x4*)(xf + base + kf * 512 + l * 8) = cv.u;
  }
}

// ---------------------------------------------------------------------------
__device__ __forceinline__ void stage_whh(const u16* src, char* smem, int tid){
  #pragma unroll
  for (int it = 0; it < 16; ++it)
    gl_lds16(src + it * 4096 + tid * 8, smem + it * 8192 + tid * 16);
}

// fp16 x-weight fragments for the 2x2 split: wave covers cols [cs*64, cs*64+64)
__device__ __forceinline__ void load_xwH(const u16* xwbase, int cs, int lane,
                                         f16x8 (&whiF)[2][4]){
  #pragma unroll
  for (int ks = 0; ks < 2; ++ks)
    #pragma unroll
    for (int ni = 0; ni < 4; ++ni) {
      int strip = cs * 2 + (ni >> 1);
      whiF[ks][ni] = ld_f8(xwbase + (size_t)strip * 2048 +
                           (ks * 2 + (ni & 1)) * 512 + lane * 8);
    }
}

__device__ __forceinline__ void wave_arrive(u32* gcnt, u32* lcnt, int lane,
                                            int fast, int& ev){
  asm volatile("s_waitcnt vmcnt(0)" ::: "memory");
  u32 old = 0;
  if (lane == 0) old = atomicAdd(lcnt, 1u);
  old = __builtin_amdgcn_readfirstlane(old);
  if ((old & 3u) == 3u) {
    if (lane == 0) {
      if (fast) {
        asm volatile("global_atomic_add %0, %1, off" :: "v"(gcnt), "v"(1u) : "memory");
      } else {
        __hip_atomic_fetch_add(gcnt, 1u, __ATOMIC_RELAXED, __HIP_MEMORY_SCOPE_AGENT);
      }
    }
    asm volatile("s_waitcnt vmcnt(0)" ::: "memory");
  }
  ++ev;
}

__device__ __forceinline__ void wave_wait(u32* gcnt, u32* lflag, int lane,
                                          int leader, int fast, int ev){
  u32 target = (u32)ev * 16u;
  if (leader) {
    if (fast) {
      for (;;) {
        u32 v = 0;
        if (lane == 0)
          asm volatile("global_atomic_or %0, %1, %2, off sc0\n\ts_waitcnt vmcnt(0)"
                       : "=v"(v) : "v"(gcnt), "v"(0u) : "memory");
        v = __builtin_amdgcn_readfirstlane(v);
        if (v >= target) break;
        __builtin_amdgcn_s_sleep(1);
      }
      asm volatile("buffer_inv" ::: "memory");
    } else {
      for (;;) {
        u32 v = 0;
        if (lane == 0)
          v = __hip_atomic_load(gcnt, __ATOMIC_RELAXED, __HIP_MEMORY_SCOPE_AGENT);
        v = __builtin_amdgcn_readfirstlane(v);
        if (v >= target) break;
        __builtin_amdgcn_s_sleep(1);
      }
      __builtin_amdgcn_fence(__ATOMIC_ACQUIRE, "agent");
    }
    if (lane == 0)
      __hip_atomic_store(lflag, (u32)ev, __ATOMIC_RELAXED, __HIP_MEMORY_SCOPE_WORKGROUP);
    asm volatile("s_waitcnt lgkmcnt(0)" ::: "memory");
  } else {
    for (;;) {
      u32 f = 0;
      if (lane == 0)
        f = __hip_atomic_load(lflag, __ATOMIC_RELAXED, __HIP_MEMORY_SCOPE_WORKGROUP);
      f = __builtin_amdgcn_readfirstlane(f);
      if (f >= (u32)ev) break;
      __builtin_amdgcn_s_sleep(1);
    }
  }
}

__device__ __forceinline__ void issue_h2(const u16* h_in, int rbase, int lane,
                                         int kb, U4B (&dst)[4]){
  #pragma unroll
  for (int ks = 0; ks < 2; ++ks)
    #pragma unroll
    for (int mi = 0; mi < 2; ++mi) {
      const u16* p = h_in + (size_t)(rbase + mi) * 8192 + (kb * 2 + ks) * 512
                     + (lane >> 4) * 128 + (lane & 15) * 8;
      GLD16(dst[ks * 2 + mi].u, p);
    }
}

// prefetch next step's x fragments (4 x 16B) into registers
__device__ __forceinline__ void pref_x(const u16* xf, int tx, int rbase, int lane,
                                       U4H (&pfn)[2][2]){
  #pragma unroll
  for (int mi = 0; mi < 2; ++mi)
    #pragma unroll
    for (int kf = 0; kf < 2; ++kf)
      GLD16(pfn[mi][kf].u,
            xf + ((size_t)tx * 128 + rbase + mi) * 1024 + kf * 512 + lane * 8);
}

// ---------------------------------------------------------------------------
__global__ __launch_bounds__(512, 1) void lstm_persistent(
    const float* __restrict__ x, const u16* __restrict__ xf, int use_xf,
    const u16* __restrict__ WhhE, const u16* __restrict__ WhhD,
    const u16* __restrict__ xwE, const u16* __restrict__ xwD,
    const float* __restrict__ biasE, const float* __restrict__ biasD,
    u16* __restrict__ hb0, u16* __restrict__ hb1,
    float* __restrict__ dout,
    const float* __restrict__ WdT, const float* __restrict__ ldb,
    const float* __restrict__ loW, const float* __restrict__ lob,
    float* __restrict__ out, u32* __restrict__ cnt, u32* __restrict__ xcc)
{
  extern __shared__ char smem[];
  __shared__ u32 chaincnt[2];
  __shared__ u32 chainflag[2];
  const int tid = threadIdx.x;
  const int bid = blockIdx.x;
  const int mt = ((bid & 7) << 1) | ((bid >> 3) & 1);
  const int nt = bid >> 4;
  const int wid = tid >> 6, lane = tid & 63;
  const int mh = wid >> 2, sub = wid & 3;    // chain = mh; sub -> 2x2 tile
  const int rs = sub >> 1, cs = sub & 1;
  const int leader = (sub == 0) ? 1 : 0;
  const int lr = lane & 15, lgp = lane >> 4;
  const int rbase = mt * 8 + mh * 4 + rs * 2;
  u32* ccnt = cnt + (mt * 2 + mh) * 16;
  u32* pcnt = cnt + 512 + mt * 16;
  u32* cflag = &chainflag[mh];

  stage_whh(WhhE + (size_t)nt * WIMG2, smem, tid);
  f16x8 whiF[2][4];
  load_xwH(xwE + (size_t)nt * 8192, cs, lane, whiF);
  f32x4 bvec[4];
  #pragma unroll
  for (int ni = 0; ni < 4; ++ni)
    bvec[ni] = *(const f32x4*)(biasE + nt * 128 + cs * 64 + ni * 16 + lgp * 4);

  // ---- prologue: publish XCC id, safe barrier, verify group co-location ----
  u32 myxcc;
  asm volatile("s_getreg_b32 %0, hwreg(HW_REG_XCC_ID)" : "=s"(myxcc));
  if (tid == 0) {
    chaincnt[0] = 0; chaincnt[1] = 0;
    chainflag[0] = 0; chainflag[1] = 0;
    HST32(xcc + bid, myxcc);
  }
  asm volatile("s_waitcnt vmcnt(0)" ::: "memory");
  __syncthreads();
  if (tid == 0) {
    __hip_atomic_fetch_add(pcnt, 1u, __ATOMIC_RELAXED, __HIP_MEMORY_SCOPE_AGENT);
    while (__hip_atomic_load(pcnt, __ATOMIC_RELAXED, __HIP_MEMORY_SCOPE_AGENT) < 16u)
      __builtin_amdgcn_s_sleep(1);
    __builtin_amdgcn_fence(__ATOMIC_ACQUIRE, "agent");
  }
  __syncthreads();
  int fast = 1;
  {
    int gb = (mt >> 1) | ((mt & 1) << 3);
    #pragma unroll
    for (int k = 0; k < 16; ++k) {
      u32 v;
      asm volatile("global_load_dword %0, %1, off sc0 sc1\n\ts_waitcnt vmcnt(0)"
                   : "=v"(v) : "v"(xcc + gb + k * 16));
      fast &= (v == myxcc) ? 1 : 0;
    }
  }
  __syncthreads();

  U4H pfn[2][2];
  if (use_xf) {
    pref_x(xf, 0, rbase, lane, pfn);
    asm volatile("s_waitcnt vmcnt(0)" ::: "memory");
  }

  float creg[2][4];
  #pragma unroll
  for (int a = 0; a < 2; ++a)
    #pragma unroll
    for (int b = 0; b < 4; ++b) creg[a][b] = 0.f;

  int ev = 0;

  // ================= encoder: x -> wait -> h -> pref -> epi -> arrive =========
  for (int t = 0; t < TENC; ++t) {
    const u16* __restrict__ h_in  = (t & 1) ? hb1 : hb0;
    u16*       __restrict__ h_out = (t & 1) ? hb0 : hb1;

    f32x4 acc[2][4];
    #pragma unroll
    for (int a = 0; a < 2; ++a)
      #pragma unroll
      for (int b = 0; b < 4; ++b) acc[a][b] = bvec[b];   // bias pre-loaded

    if (use_xf) {
      __builtin_amdgcn_sched_barrier(0);   // pfn completed by arrive's vmcnt(0)
      #pragma unroll
      for (int mi = 0; mi < 2; ++mi) {
        f16x8 x0 = pfn[mi][0].h, x1 = pfn[mi][1].h;
        #pragma unroll
        for (int ni = 0; ni < 4; ++ni) {
          acc[mi][ni] = MFMA16H(whiF[0][ni], x0, acc[mi][ni], 0, 0, 0);
          acc[mi][ni] = MFMA16H(whiF[1][ni], x1, acc[mi][ni], 0, 0, 0);
        }
      }
    } else {
      #pragma unroll
      for (int mi = 0; mi < 2; ++mi) {
        int brow = (rbase + mi) * 16 + lr;
        const float* p = x + ((size_t)brow * 256 + t) * 64;
        #pragma unroll
        for (int ks = 0; ks < 2; ++ks) {
          float fv[8];
          #pragma unroll
          for (int e = 0; e < 8; ++e) fv[e] = p[ks * 32 + lgp * 8 + e];
          f16x8 xk = cvtf16(fv);
          #pragma unroll
          for (int ni = 0; ni < 4; ++ni)
            acc[mi][ni] = MFMA16H(whiF[ks][ni], xk, acc[mi][ni], 0, 0, 0);
        }
      }
    }

    wave_wait(ccnt, cflag, lane, leader, fast, ev);

    // ---- h phase: 4 loads/kb, depth-4 pipeline (16 in flight) ----
    {
      U4B hr[4][4];
      issue_h2(h_in, rbase, lane, 0, hr[0]);
      issue_h2(h_in, rbase, lane, 1, hr[1]);
      issue_h2(h_in, rbase, lane, 2, hr[2]);
      #pragma unroll
      for (int kb = 0; kb < 8; ++kb) {
        if (kb < 5) issue_h2(h_in, rbase, lane, kb + 3, hr[(kb + 3) & 3]);
        if (kb < 5)       { asm volatile("s_waitcnt vmcnt(12)" ::: "memory"); }
        else if (kb == 5) { asm volatile("s_waitcnt vmcnt(8)" ::: "memory"); }
        else if (kb == 6) { asm volatile("s_waitcnt vmcnt(4)" ::: "memory"); }
        else              { asm volatile("s_waitcnt vmcnt(0)" ::: "memory"); }
        __builtin_amdgcn_sched_barrier(0);
        #pragma unroll
        for (int ks = 0; ks < 2; ++ks) {
          bf16x8 wf[4];
          #pragma unroll
          for (int ni = 0; ni < 4; ++ni) {
            int crow = cs * 64 + ni * 16 + lr;
            wf[ni] = *(const bf16x8*)(smem + kb * 16384 + crow * 128 +
                                      (((ks * 4 + lgp) ^ (crow & 7)) << 4));
          }
          #pragma unroll
          for (int mi = 0; mi < 2; ++mi)
            #pragma unroll
            for (int ni = 0; ni < 4; ++ni)
              acc[mi][ni] = MFMA16(wf[ni], hr[kb & 3][ks * 2 + mi].b, acc[mi][ni], 0, 0, 0);
        }
      }
    }

    // ---- prefetch next x (hidden under epilogue + arrive) ----
    if (use_xf) {
      int txn = (t + 1 < TENC) ? (t + 1) : 255;   // t=255 -> decoder d0 input
      pref_x(xf, txn, rbase, lane, pfn);
    }

    // ---- fused LSTM epilogue ----
    #pragma unroll
    for (int mi = 0; mi < 2; ++mi) {
      #pragma unroll
      for (int nip = 0; nip < 2; ++nip) {
        float hn2[2];
        #pragma unroll
        for (int s2 = 0; s2 < 2; ++s2) {
          int ni = nip * 2 + s2;
          f32x4 g = acc[mi][ni];
          float c0 = creg[mi][ni];
          float cn = sigm(g[1]) * c0 + sigm(g[0]) * tanhfast(g[2]);
          hn2[s2] = sigm(g[3]) * tanhfast(cn);
          creg[mi][ni] = cn;
        }
        u32 pk = pk_bf16(hn2[0], hn2[1]);
        u16* p = h_out + (size_t)(rbase + mi) * 8192 + nt * 512 +
                 (cs * 2 + nip) * 128 + lr * 8 + lgp * 2;
        if (fast) { GST32(p, pk); } else { HST32(p, pk); }
      }
    }
    wave_arrive(ccnt, &chaincnt[mh], lane, fast, ev);   // drains pfn loads too
  }

  // ================= weight swap =================
  __syncthreads();
  stage_whh(WhhD + (size_t)nt * WIMG2, smem, tid);
  load_xwH(xwD + (size_t)nt * 8192, cs, lane, whiF);
  #pragma unroll
  for (int ni = 0; ni < 4; ++ni)
    bvec[ni] = *(const f32x4*)(biasD + nt * 128 + cs * 64 + ni * 16 + lgp * 4);
  asm volatile("s_waitcnt vmcnt(0)" ::: "memory");
  __syncthreads();

  // ================= decoder =================
  for (int d = 0; d < TDEC; ++d) {
    int t = TENC + d;
    const u16* __restrict__ h_in  = (t & 1) ? hb1 : hb0;
    u16*       __restrict__ h_out = (t & 1) ? hb0 : hb1;

    f32x4 acc[2][4];
    #pragma unroll
    for (int a = 0; a < 2; ++a)
      #pragma unroll
      for (int b = 0; b < 4; ++b) acc[a][b] = bvec[b];

    if (d == 0) {
      if (use_xf) {
        __builtin_amdgcn_sched_barrier(0);   // pfn (tx=255) done since t=255 arrive
        #pragma unroll
        for (int mi = 0; mi < 2; ++mi) {
          f16x8 x0 = pfn[mi][0].h, x1 = pfn[mi][1].h;
          #pragma unroll
          for (int ni = 0; ni < 4; ++ni) {
            acc[mi][ni] = MFMA16H(whiF[0][ni], x0, acc[mi][ni], 0, 0, 0);
            acc[mi][ni] = MFMA16H(whiF[1][ni], x1, acc[mi][ni], 0, 0, 0);
          }
        }
      } else {
        #pragma unroll
        for (int mi = 0; mi < 2; ++mi) {
          int brow = (rbase + mi) * 16 + lr;
          const float* p = x + ((size_t)brow * 256 + 255) * 64;
          #pragma unroll
          for (int ks = 0; ks < 2; ++ks) {
            float fv[8];
            #pragma unroll
            for (int e = 0; e < 8; ++e) fv[e] = p[ks * 32 + lgp * 8 + e];
            f16x8 xk = cvtf16(fv);
            #pragma unroll
            for (int ni = 0; ni < 4; ++ni)
              acc[mi][ni] = MFMA16H(whiF[ks][ni], xk, acc[mi][ni], 0, 0, 0);
          }
        }
      }
      wave_wait(ccnt, cflag, lane, leader, fast, ev);
    } else {
      wave_wait(ccnt, cflag, lane, leader, fast, ev);   // dout + h(t-1) ready
      #pragma unroll
      for (int mi = 0; mi < 2; ++mi) {
        int brow = (rbase + mi) * 16 + lr;
        const float* p = dout + (size_t)brow * 64 + lgp * 8;
        #pragma unroll
        for (int ks = 0; ks < 2; ++ks) {
          float fv[8];
          float4 a0 = *(const float4*)(p + ks * 32);
          float4 a1 = *(const float4*)(p + ks * 32 + 4);
          fv[0]=a0.x; fv[1]=a0.y; fv[2]=a0.z; fv[3]=a0.w;
          fv[4]=a1.x; fv[5]=a1.y; fv[6]=a1.z; fv[7]=a1.w;
          f16x8 xk = cvtf16(fv);
          #pragma unroll
          for (int ni = 0; ni < 4; ++ni)
            acc[mi][ni] = MFMA16H(whiF[ks][ni], xk, acc[mi][ni], 0, 0, 0);
        }
      }
    }

    {
      U4B hr[4][4];
      issue_h2(h_in, rbase, lane, 0, hr[0]);
      issue_h2(h_in, rbase, lane, 1, hr[1]);
      issue_h2(h_in, rbase, lane, 2, hr[2]);
      #pragma unroll
      for (int kb = 0; kb < 8; ++kb) {
        if (kb < 5) issue_h2(h_in, rbase, lane, kb + 3, hr[(kb + 3) & 3]);
        if (kb < 5)       { asm volatile("s_waitcnt vmcnt(12)" ::: "memory"); }
        else if (kb == 5) { asm volatile("s_waitcnt vmcnt(8)" ::: "memory"); }
        else if (kb == 6) { asm volatile("s_waitcnt vmcnt(4)" ::: "memory"); }
        else              { asm volatile("s_waitcnt vmcnt(0)" ::: "memory"); }
        __builtin_amdgcn_sched_barrier(0);
        #pragma unroll
        for (int ks = 0; ks < 2; ++ks) {
          bf16x8 wf[4];
          #pragma unroll
          for (int ni = 0; ni < 4; ++ni) {
            int crow = cs * 64 + ni * 16 + lr;
            wf[ni] = *(const bf16x8*)(smem + kb * 16384 + crow * 128 +
                                      (((ks * 4 + lgp) ^ (crow & 7)) << 4));
          }
          #pragma unroll
          for (int mi = 0; mi < 2; ++mi)
            #pragma unroll
            for (int ni = 0; ni < 4; ++ni)
              acc[mi][ni] = MFMA16(wf[ni], hr[kb & 3][ks * 2 + mi].b, acc[mi][ni], 0, 0, 0);
        }
      }
    }

    #pragma unroll
    for (int mi = 0; mi < 2; ++mi) {
      #pragma unroll
      for (int nip = 0; nip < 2; ++nip) {
        float hn2[2];
        #pragma unroll
        for (int s2 = 0; s2 < 2; ++s2) {
          int ni = nip * 2 + s2;
          f32x4 g = acc[mi][ni];
          float c0 = creg[mi][ni];
          float cn = sigm(g[1]) * c0 + sigm(g[0]) * tanhfast(g[2]);
          hn2[s2] = sigm(g[3]) * tanhfast(cn);
          creg[mi][ni] = cn;
        }
        u32 pk = pk_bf16(hn2[0], hn2[1]);
        u16* p = h_out + (size_t)(rbase + mi) * 8192 + nt * 512 +
                 (cs * 2 + nip) * 128 + lr * 8 + lgp * 2;
        if (fast) { GST32(p, pk); } else { HST32(p, pk); }
      }
    }
    wave_arrive(ccnt, &chaincnt[mh], lane, fast, ev);
    wave_wait(ccnt, cflag, lane, leader, fast, ev);

    // ---- dec-proj: one row per wave, chain-local rows ----
    {
      int b = mt * 128 + mh * 64 + nt * 4 + sub;
      int rb = b >> 4, lrb = b & 15;
      const u16* hbase = h_out + (size_t)rb * 8192 + lrb * 8;
      float a2 = ldb[lane];
      #pragma unroll 8
      for (int q = 0; q < 64; ++q) {
        uint4 hv = *(const uint4*)(hbase + q * 128);
        #pragma unroll
        for (int e = 0; e < 8; ++e) {
          float h8 = bf2f(((const u16*)&hv)[e]);
          a2 += h8 * WdT[(q * 8 + e) * 64 + lane];
        }
      }
      float* dp = dout + (size_t)b * 64 + lane;
      if (fast) { GST32(dp, __float_as_uint(a2)); } else { HST32(dp, __float_as_uint(a2)); }
      float yv = a2 * loW[lane];
      #pragma unroll
      for (int o2 = 32; o2; o2 >>= 1) yv += __shfl_xor(yv, o2, 64);
      if (lane == 0) out[(size_t)b * TDEC + d] = yv + lob[0];
    }
    if (d < TDEC - 1) wave_arrive(ccnt, &chaincnt[mh], lane, fast, ev);
  }
}

// ---------------------------------------------------------------------------
extern "C" void kernel_launch(void* const* d_in, const int* in_sizes, int n_in,
                              void* d_out, int out_size, void* d_ws, size_t ws_size,
                              hipStream_t stream)
{
  const float* x    = (const float*)d_in[0];
  const float* eWih = (const float*)d_in[1];
  const float* eWhh = (const float*)d_in[2];
  const float* ebih = (const float*)d_in[3];
  const float* ebhh = (const float*)d_in[4];
  const float* dWih = (const float*)d_in[5];
  const float* dWhh = (const float*)d_in[6];
  const float* dbih = (const float*)d_in[7];
  const float* dbhh = (const float*)d_in[8];
  const float* ldW  = (const float*)d_in[9];
  const float* ldbp = (const float*)d_in[10];
  const float* loW  = (const float*)d_in[11];
  const float* lob  = (const float*)d_in[12];
  float* out = (float*)d_out;

  char* ws = (char*)d_ws;
  size_t o = 0;
  auto alloc = [&](size_t bytes){ size_t r = o; o += (bytes + 255) & ~(size_t)255; return r; };
  u16*   WhhIE = (u16*)  (ws + alloc((size_t)16 * WIMG2 * 2));
  u16*   WhhID = (u16*)  (ws + alloc((size_t)16 * WIMG2 * 2));
  u16*   xwE   = (u16*)  (ws + alloc((size_t)64 * 4 * 512 * 2));
  u16*   xwD   = (u16*)  (ws + alloc((size_t)64 * 4 * 512 * 2));
  float* biasE = (float*)(ws + alloc(2048 * 4));
  float* biasD = (float*)(ws + alloc(2048 * 4));
  float* WdT   = (float*)(ws + alloc((size_t)I_ * H_ * 4));
  u16*   hb0   = (u16*)  (ws + alloc((size_t)B_ * H_ * 2));
  u16*   hb1   = (u16*)  (ws + alloc((size_t)B_ * H_ * 2));
  float* dout  = (float*)(ws + alloc((size_t)B_ * I_ * 4));
  u32*   cnt   = (u32*)  (ws + alloc(4096));
  u32*   xcc   = (u32*)  (ws + alloc(1024));
  size_t xf_off = alloc((size_t)256 * 128 * 1024 * 2);   // 64 MiB (fp16)
  int use_xf = (o <= ws_size) ? 1 : 0;
  u16* xf = use_xf ? (u16*)(ws + xf_off) : (u16*)(ws);
  (void)in_sizes; (void)n_in; (void)out_size;

  pack_whh<<<(16 * WIMG2 + 255) / 256, 256, 0, stream>>>(eWhh, WhhIE);
  pack_whh<<<(16 * WIMG2 + 255) / 256, 256, 0, stream>>>(dWhh, WhhID);
  pack_xw<<<(64 * 4 * 512 + 255) / 256, 256, 0, stream>>>(eWih, xwE);
  pack_xw<<<(64 * 4 * 512 + 255) / 256, 256, 0, stream>>>(dWih, xwD);
  pack_bias<<<8, 256, 0, stream>>>(ebih, ebhh, biasE);
  pack_bias<<<8, 256, 0, stream>>>(dbih, dbhh, biasD);
  transpose_wd<<<(I_ * H_ + 255) / 256, 256, 0, stream>>>(ldW, WdT);
  if (use_xf)
    prefrag_x<<<256 * 128, 64, 0, stream>>>(x, xf);
  (void)hipMemsetAsync(hb0, 0, (size_t)B_ * H_ * 2, stream);
  (void)hipMemsetAsync(cnt, 0, 4096, stream);

  static bool attr_set = false;
  if (!attr_set) {
    (void)hipFuncSetAttribute((const void*)lstm_persistent,
                              hipFuncAttributeMaxDynamicSharedMemorySize, 131072);
    attr_set = true;
  }

  const float* xp = x; const u16* xfp = xf; int uxf = use_xf;
  const u16 *we = WhhIE, *wd = WhhID, *xe = xwE, *xd = xwD;
  const float *be = biasE, *bd = biasD, *wdt = WdT, *lb = ldbp, *lw = loW, *lo2 = lob;
  u16 *h0 = hb0, *h1 = hb1;
  float *dp = dout, *op = out;
  u32* cp = cnt; u32* xc = xcc;
  void* kargs[] = { (void*)&xp, (void*)&xfp, (void*)&uxf, (void*)&we, (void*)&wd,
                    (void*)&xe, (void*)&xd, (void*)&be, (void*)&bd,
                    (void*)&h0, (void*)&h1, (void*)&dp, (void*)&wdt,
                    (void*)&lb, (void*)&lw, (void*)&lo2, (void*)&op, (void*)&cp,
                    (void*)&xc };
  hipError_t e = hipLaunchCooperativeKernel((const void*)lstm_persistent,
                                            dim3(256), dim3(512), kargs, 131072, stream);
  if (e != hipSuccess) {
    lstm_persistent<<<256, 512, 131072, stream>>>(xp, xfp, uxf, we, wd, xe, xd,
                                                  be, bd, h0, h1, dp, wdt,
                                                  lb, lw, lo2, op, cp, xc);
  }
}